// Round 1
// 1857.314 us; speedup vs baseline: 1.3238x; 1.3238x over previous
//
#include <hip/hip_runtime.h>
#include <cstdint>
#include <cstddef>

#define BATCH_ 2
#define SEQ_ 2048
#define DM 768      // d_model
#define DH 1536     // d_inner
#define NS 16       // d_state
#define RK 48       // dt_rank
#define MR (BATCH_*SEQ_)   // 4096 rows
#define NCH 32      // scan chunks
#define CL (SEQ_/NCH)      // 64 steps per chunk
#define NCHAN (2*BATCH_*DH)        // 6144 (dir,b,d) channels
#define NDBLK (DH/256)             // 6 d-blocks per (dir,b,chunk)

__device__ __forceinline__ float sigmoidf_(float x){ return 1.f/(1.f+__expf(-x)); }

// ---------------- LayerNorm 1: writes xn and time-reversed xn ----------------
__global__ __launch_bounds__(256) void ln1_kernel(const float* __restrict__ x,
    const float* __restrict__ g, const float* __restrict__ bta,
    float* __restrict__ xn, float* __restrict__ xnr)
{
  int row = blockIdx.x;            // b*SEQ + l
  int tid = threadIdx.x;
  int bb = row >> 11, l = row & (SEQ_-1);
  __shared__ float s1[256], s2[256];
  float v[3]; float sum=0.f, sq=0.f;
  const float* xr = x + (size_t)row*DM;
  #pragma unroll
  for (int i=0;i<3;i++){ v[i] = xr[tid + i*256]; sum += v[i]; sq += v[i]*v[i]; }
  s1[tid]=sum; s2[tid]=sq; __syncthreads();
  for (int off=128; off>0; off>>=1){
    if (tid<off){ s1[tid]+=s1[tid+off]; s2[tid]+=s2[tid+off]; }
    __syncthreads();
  }
  float mean = s1[0] * (1.f/DM);
  float var  = s2[0] * (1.f/DM) - mean*mean;
  float rstd = rsqrtf(var + 1e-5f);
  size_t rrow = ((size_t)bb*SEQ_ + (SEQ_-1-l))*DM;
  #pragma unroll
  for (int i=0;i<3;i++){
    int c = tid + i*256;
    float val = (v[i]-mean)*rstd*g[c] + bta[c];
    xn[(size_t)row*DM + c] = val;
    xnr[rrow + c] = val;
  }
}

// ---------------- LayerNorm 2: m = LN(fo + reverse(bo)) ----------------
__global__ __launch_bounds__(256) void ln2_kernel(const float* __restrict__ fo,
    const float* __restrict__ bo, const float* __restrict__ g,
    const float* __restrict__ bta, float* __restrict__ m)
{
  int row = blockIdx.x;
  int tid = threadIdx.x;
  int bb = row >> 11, l = row & (SEQ_-1);
  __shared__ float s1[256], s2[256];
  size_t rrow = ((size_t)bb*SEQ_ + (SEQ_-1-l))*DM;
  float v[3]; float sum=0.f, sq=0.f;
  #pragma unroll
  for (int i=0;i<3;i++){
    int c = tid + i*256;
    v[i] = fo[(size_t)row*DM + c] + bo[rrow + c];
    sum += v[i]; sq += v[i]*v[i];
  }
  s1[tid]=sum; s2[tid]=sq; __syncthreads();
  for (int off=128; off>0; off>>=1){
    if (tid<off){ s1[tid]+=s1[tid+off]; s2[tid]+=s2[tid+off]; }
    __syncthreads();
  }
  float mean = s1[0] * (1.f/DM);
  float var  = s2[0] * (1.f/DM) - mean*mean;
  float rstd = rsqrtf(var + 1e-5f);
  #pragma unroll
  for (int i=0;i<3;i++){
    int c = tid + i*256;
    m[(size_t)row*DM + c] = (v[i]-mean)*rstd*g[c] + bta[c];
  }
}

// ---------------- small tiled GEMM (skinny N or K): C = act(A W^T + bias) ----
// ACT: 0=none, 1=softplus
template<int ACT>
__global__ __launch_bounds__(256) void gemm_nt(const float* __restrict__ A, int lda,
    const float* __restrict__ W, const float* __restrict__ bias,
    float* __restrict__ C, int ldc, const float* __restrict__ res,
    int M, int N, int K)
{
  __shared__ float As[16][64];
  __shared__ float Ws[16][64];
  int tid = threadIdx.x;
  int tx = tid & 15, ty = tid >> 4;
  int m0 = blockIdx.y * 64, n0 = blockIdx.x * 64;
  int lm = tid >> 2;          // 0..63
  int lk = (tid & 3) * 4;     // 0,4,8,12
  float acc[4][4] = {};
  for (int k0 = 0; k0 < K; k0 += 16) {
    float4 av = *(const float4*)(A + (size_t)(m0+lm)*lda + k0 + lk);
    As[lk+0][lm] = av.x; As[lk+1][lm] = av.y; As[lk+2][lm] = av.z; As[lk+3][lm] = av.w;
    int wn = n0 + lm;
    float4 wv = make_float4(0.f,0.f,0.f,0.f);
    if (wn < N) wv = *(const float4*)(W + (size_t)wn*K + k0 + lk);
    Ws[lk+0][lm] = wv.x; Ws[lk+1][lm] = wv.y; Ws[lk+2][lm] = wv.z; Ws[lk+3][lm] = wv.w;
    __syncthreads();
    #pragma unroll
    for (int k = 0; k < 16; ++k) {
      float4 a = *(const float4*)&As[k][ty*4];
      float4 w = *(const float4*)&Ws[k][tx*4];
      acc[0][0] += a.x*w.x; acc[0][1] += a.x*w.y; acc[0][2] += a.x*w.z; acc[0][3] += a.x*w.w;
      acc[1][0] += a.y*w.x; acc[1][1] += a.y*w.y; acc[1][2] += a.y*w.z; acc[1][3] += a.y*w.w;
      acc[2][0] += a.z*w.x; acc[2][1] += a.z*w.y; acc[2][2] += a.z*w.z; acc[2][3] += a.z*w.w;
      acc[3][0] += a.w*w.x; acc[3][1] += a.w*w.y; acc[3][2] += a.w*w.z; acc[3][3] += a.w*w.w;
    }
    __syncthreads();
  }
  #pragma unroll
  for (int i=0;i<4;i++){
    int row = m0 + ty*4 + i;
    #pragma unroll
    for (int j=0;j<4;j++){
      int col = n0 + tx*4 + j;
      if (col < N) {
        float vv = acc[i][j];
        if (bias) vv += bias[col];
        if (ACT == 1) vv = (vv > 20.f) ? vv : log1pf(expf(vv));            // softplus
        if (res) vv += res[(size_t)row*ldc + col];
        C[(size_t)row*ldc + col] = vv;
      }
    }
  }
}

// ---------------- big tiled GEMM: BM x 128 tile, 8-col x TM-row microtile ----
// Fragments split as {g, 64+g} groups of 4 -> all LDS reads <=2-way (free).
// Requires M%BM==0, N%128==0, K%16==0.  ACT: 0=none, 2=gelu(exact)
template<int BM, int ACT>
__global__ __launch_bounds__(256) void gemm_big(const float* __restrict__ A, int lda,
    const float* __restrict__ W, const float* __restrict__ bias,
    float* __restrict__ C, int ldc, const float* __restrict__ res,
    int M, int N, int K)
{
  constexpr int TM = BM/16;                 // 8 (BM=128) or 4 (BM=64)
  __shared__ float As[16][BM];
  __shared__ float Ws[16][128];
  const int tid = threadIdx.x;
  const int m0 = blockIdx.y * BM, n0 = blockIdx.x * 128;
  const int tx = tid & 15, ty = tid >> 4;

  int lrA, lkA;
  if constexpr (BM == 128) { lrA = tid >> 1; lkA = (tid & 1) * 8; }
  else                     { lrA = tid >> 2; lkA = (tid & 3) * 4; }
  const int lrW = tid >> 1, lkW = (tid & 1) * 8;
  const float* Ap = A + (size_t)(m0 + lrA) * lda + lkA;
  const float* Wp = W + (size_t)(n0 + lrW) * K + lkW;

  float acc[TM][8];
  #pragma unroll
  for (int i=0;i<TM;i++)
    #pragma unroll
    for (int j=0;j<8;j++) acc[i][j] = 0.f;

  for (int k0 = 0; k0 < K; k0 += 16) {
    float4 a0 = *(const float4*)(Ap + k0);
    float4 a1 = make_float4(0.f,0.f,0.f,0.f);
    if constexpr (BM == 128) a1 = *(const float4*)(Ap + k0 + 4);
    float4 w0 = *(const float4*)(Wp + k0);
    float4 w1 = *(const float4*)(Wp + k0 + 4);
    __syncthreads();
    As[lkA+0][lrA]=a0.x; As[lkA+1][lrA]=a0.y; As[lkA+2][lrA]=a0.z; As[lkA+3][lrA]=a0.w;
    if constexpr (BM == 128) {
      As[lkA+4][lrA]=a1.x; As[lkA+5][lrA]=a1.y; As[lkA+6][lrA]=a1.z; As[lkA+7][lrA]=a1.w;
    }
    Ws[lkW+0][lrW]=w0.x; Ws[lkW+1][lrW]=w0.y; Ws[lkW+2][lrW]=w0.z; Ws[lkW+3][lrW]=w0.w;
    Ws[lkW+4][lrW]=w1.x; Ws[lkW+5][lrW]=w1.y; Ws[lkW+6][lrW]=w1.z; Ws[lkW+7][lrW]=w1.w;
    __syncthreads();
    #pragma unroll
    for (int k = 0; k < 16; ++k) {
      float wv[8], av[TM];
      *(float4*)&wv[0] = *(const float4*)&Ws[k][tx*4];
      *(float4*)&wv[4] = *(const float4*)&Ws[k][64 + tx*4];
      *(float4*)&av[0] = *(const float4*)&As[k][ty*4];
      if constexpr (BM == 128)
        *(float4*)&av[4] = *(const float4*)&As[k][64 + ty*4];
      #pragma unroll
      for (int i=0;i<TM;i++)
        #pragma unroll
        for (int j=0;j<8;j++)
          acc[i][j] = fmaf(av[i], wv[j], acc[i][j]);
    }
  }
  #pragma unroll
  for (int i=0;i<TM;i++){
    int row = m0 + ((i < 4) ? (ty*4 + i) : (64 + ty*4 + i - 4));
    #pragma unroll
    for (int jj=0;jj<2;jj++){
      int colb = n0 + jj*64 + tx*4;
      float vv[4];
      #pragma unroll
      for (int j=0;j<4;j++){
        float t = acc[i][jj*4 + j];
        if (bias) t += bias[colb + j];
        if constexpr (ACT == 2) t = 0.5f*t*(1.f + erff(t*0.70710678118654752f));
        if (res) t += res[(size_t)row*ldc + colb + j];
        vv[j] = t;
      }
      *(float4*)(C + (size_t)row*ldc + colb) = make_float4(vv[0],vv[1],vv[2],vv[3]);
    }
  }
}

// ---------------- depthwise causal conv(4) + SiLU ----------------
__global__ __launch_bounds__(256) void conv_silu_kernel(const float* __restrict__ xz,
    const float* __restrict__ cw, const float* __restrict__ cb, float* __restrict__ xh)
{
  int idx = blockIdx.x*256 + threadIdx.x;   // over MR*DH
  int d = idx % DH;
  int row = idx / DH;
  int l = row & (SEQ_-1);
  const float* base = xz + (size_t)row*(2*DH) + d;
  float acc = cb[d];
  #pragma unroll
  for (int j=0;j<4;j++){
    int ll = l - 3 + j;
    if (ll >= 0) acc += cw[d*4+j] * base[(ptrdiff_t)(j-3)*(2*DH)];
  }
  xh[(size_t)row*DH + d] = acc * sigmoidf_(acc);
}

// ================= chunked selective scan, d-coalesced =================
// One THREAD per (dir,b,chunk,d): all 16 states in registers. Consecutive
// threads = consecutive d -> dt/xh/z/yg fully coalesced. B/C staged in LDS
// per chunk (broadcast reads). Block = 256 d's; grid = 4(db) x NCH x NDBLK.

// Phase 1: local scan from h=0 over CL steps -> hend[unit*NS+n], dtsum.
__global__ __launch_bounds__(256) void scan_p1_kernel(
    const float* __restrict__ dt0, const float* __restrict__ xh0, const float* __restrict__ xd0,
    const float* __restrict__ Al0,
    const float* __restrict__ dt1, const float* __restrict__ xh1, const float* __restrict__ xd1,
    const float* __restrict__ Al1,
    float* __restrict__ hend, float* __restrict__ dtsum)
{
  int tid = threadIdx.x;
  int bid = blockIdx.x;
  int dblk = bid % NDBLK;
  int t   = bid / NDBLK;          // db*NCH + c
  int c   = t & (NCH-1);
  int db  = t >> 5;               // dir*2 + b
  int dir = db >> 1, bb = db & 1;
  int d = dblk*256 + tid;
  const float* dt = dir ? dt1 : dt0;
  const float* xh = dir ? xh1 : xh0;
  const float* xd = dir ? xd1 : xd0;
  const float* Al = dir ? Al1 : Al0;

  __shared__ float sB[CL][NS];    // 4 KB
  {
    const float* xdb = xd + ((size_t)bb*SEQ_ + (size_t)c*CL)*80 + RK;
    int row = tid >> 2, part = tid & 3;   // 256 float4 = CL*NS floats
    *(float4*)&sB[row][part*4] = *(const float4*)(xdb + (size_t)row*80 + part*4);
  }
  float An[NS];
  {
    const float4* ap = (const float4*)(Al + (size_t)d*NS);
    #pragma unroll
    for (int q=0;q<4;q++){
      float4 a = ap[q];
      An[4*q+0] = -__expf(a.x); An[4*q+1] = -__expf(a.y);
      An[4*q+2] = -__expf(a.z); An[4*q+3] = -__expf(a.w);
    }
  }
  __syncthreads();

  float h[NS];
  #pragma unroll
  for (int n=0;n<NS;n++) h[n] = 0.f;
  float dts = 0.f;
  size_t base = ((size_t)bb*SEQ_ + (size_t)c*CL)*DH + d;
  #pragma unroll 4
  for (int l=0;l<CL;++l){
    float dtv = dt[base], uv = xh[base];
    float du = dtv*uv;
    float Bv[NS];
    *(float4*)&Bv[0]  = *(const float4*)&sB[l][0];
    *(float4*)&Bv[4]  = *(const float4*)&sB[l][4];
    *(float4*)&Bv[8]  = *(const float4*)&sB[l][8];
    *(float4*)&Bv[12] = *(const float4*)&sB[l][12];
    #pragma unroll
    for (int n=0;n<NS;n++)
      h[n] = h[n]*__expf(dtv*An[n]) + du*Bv[n];
    dts += dtv;
    base += DH;
  }
  size_t unit = ((size_t)db*DH + d)*NCH + c;
  float4* hp = (float4*)(hend + unit*NS);
  hp[0] = make_float4(h[0],h[1],h[2],h[3]);
  hp[1] = make_float4(h[4],h[5],h[6],h[7]);
  hp[2] = make_float4(h[8],h[9],h[10],h[11]);
  hp[3] = make_float4(h[12],h[13],h[14],h[15]);
  dtsum[(size_t)c*NCHAN + (size_t)db*DH + d] = dts;   // [c][ch] layout: coalesced
}

// Phase 2: per (channel, n): sequential over NCH chunks; hend -> hstart prefix.
__global__ __launch_bounds__(256) void scan_p2_kernel(
    const float* __restrict__ Al0, const float* __restrict__ Al1,
    float* __restrict__ hend, const float* __restrict__ dtsum)
{
  int t = blockIdx.x*256 + threadIdx.x;      // 0 .. NCHAN*NS-1
  int n = t & 15;
  int ch = t >> 4;
  int d  = ch % DH;
  int dir = (ch / DH) >> 1;
  const float* Al = dir ? Al1 : Al0;
  float An = -__expf(Al[d*NS + n]);
  float h0 = 0.f;
  size_t ub = (size_t)ch * NCH;
  #pragma unroll
  for (int c = 0; c < NCH; ++c) {
    float P  = __expf(An * dtsum[(size_t)c*NCHAN + ch]);
    float he = hend[(ub + c)*NS + n];
    hend[(ub + c)*NS + n] = h0;              // now holds hstart for chunk c
    h0 = h0 * P + he;
  }
}

// Phase 3: re-run recurrence from hstart, full output + gating, in-place over xh.
__global__ __launch_bounds__(256) void scan_p3_kernel(
    const float* __restrict__ dt0, const float* __restrict__ xh0, const float* __restrict__ xd0,
    const float* __restrict__ z0, const float* __restrict__ Al0, const float* __restrict__ Dp0,
    float* __restrict__ yg0,
    const float* __restrict__ dt1, const float* __restrict__ xh1, const float* __restrict__ xd1,
    const float* __restrict__ z1, const float* __restrict__ Al1, const float* __restrict__ Dp1,
    float* __restrict__ yg1,
    const float* __restrict__ hstart)
{
  int tid = threadIdx.x;
  int bid = blockIdx.x;
  int dblk = bid % NDBLK;
  int t   = bid / NDBLK;
  int c   = t & (NCH-1);
  int db  = t >> 5;
  int dir = db >> 1, bb = db & 1;
  int d = dblk*256 + tid;
  const float* dt = dir ? dt1 : dt0;
  const float* xh = dir ? xh1 : xh0;
  const float* xd = dir ? xd1 : xd0;
  const float* zp = dir ? z1  : z0;
  const float* Al = dir ? Al1 : Al0;
  const float* Dp = dir ? Dp1 : Dp0;
  float*       yg = dir ? yg1 : yg0;

  __shared__ float sBC[CL][2*NS];   // 8 KB
  {
    const float* xdb = xd + ((size_t)bb*SEQ_ + (size_t)c*CL)*80 + RK;
    #pragma unroll
    for (int i=0;i<2;i++){
      int idx = tid + i*256;        // 512 float4 = CL*2*NS floats
      int row = idx >> 3, part = idx & 7;
      *(float4*)&sBC[row][part*4] = *(const float4*)(xdb + (size_t)row*80 + part*4);
    }
  }
  float An[NS];
  {
    const float4* ap = (const float4*)(Al + (size_t)d*NS);
    #pragma unroll
    for (int q=0;q<4;q++){
      float4 a = ap[q];
      An[4*q+0] = -__expf(a.x); An[4*q+1] = -__expf(a.y);
      An[4*q+2] = -__expf(a.z); An[4*q+3] = -__expf(a.w);
    }
  }
  float Dd = Dp[d];
  __syncthreads();

  size_t unit = ((size_t)db*DH + d)*NCH + c;
  float h[NS];
  {
    const float4* hp = (const float4*)(hstart + unit*NS);
    float4 h0=hp[0], h1=hp[1], h2=hp[2], h3=hp[3];
    h[0]=h0.x; h[1]=h0.y; h[2]=h0.z; h[3]=h0.w;
    h[4]=h1.x; h[5]=h1.y; h[6]=h1.z; h[7]=h1.w;
    h[8]=h2.x; h[9]=h2.y; h[10]=h2.z; h[11]=h2.w;
    h[12]=h3.x; h[13]=h3.y; h[14]=h3.z; h[15]=h3.w;
  }
  size_t base = ((size_t)bb*SEQ_ + (size_t)c*CL)*DH + d;
  size_t zidx = ((size_t)bb*SEQ_ + (size_t)c*CL)*(size_t)(2*DH) + d;
  #pragma unroll 2
  for (int l=0;l<CL;++l){
    float dtv = dt[base], uv = xh[base];
    float zv = zp[zidx];
    float du = dtv*uv;
    float Bv[NS], Cv[NS];
    *(float4*)&Bv[0]  = *(const float4*)&sBC[l][0];
    *(float4*)&Bv[4]  = *(const float4*)&sBC[l][4];
    *(float4*)&Bv[8]  = *(const float4*)&sBC[l][8];
    *(float4*)&Bv[12] = *(const float4*)&sBC[l][12];
    *(float4*)&Cv[0]  = *(const float4*)&sBC[l][16];
    *(float4*)&Cv[4]  = *(const float4*)&sBC[l][20];
    *(float4*)&Cv[8]  = *(const float4*)&sBC[l][24];
    *(float4*)&Cv[12] = *(const float4*)&sBC[l][28];
    float y = 0.f;
    #pragma unroll
    for (int n=0;n<NS;n++){
      h[n] = h[n]*__expf(dtv*An[n]) + du*Bv[n];
      y = fmaf(h[n], Cv[n], y);
    }
    float yv = y + uv*Dd;
    yg[base] = yv * (zv * sigmoidf_(zv));
    base += DH; zidx += 2*DH;
  }
}

template<int ACT>
static inline void launch_gemm(const float* A, int lda, const float* W, const float* bias,
                               float* C, int ldc, const float* res,
                               int M, int N, int K, hipStream_t s)
{
  dim3 grid((N+63)/64, M/64);
  gemm_nt<ACT><<<grid, dim3(256), 0, s>>>(A, lda, W, bias, C, ldc, res, M, N, K);
}

template<int BM, int ACT>
static inline void launch_gemm_big(const float* A, int lda, const float* W, const float* bias,
                                   float* C, int ldc, const float* res,
                                   int M, int N, int K, hipStream_t s)
{
  dim3 grid(N/128, M/BM);
  gemm_big<BM,ACT><<<grid, dim3(256), 0, s>>>(A, lda, W, bias, C, ldc, res, M, N, K);
}

extern "C" void kernel_launch(void* const* d_in, const int* in_sizes, int n_in,
                              void* d_out, int out_size, void* d_ws, size_t ws_size,
                              hipStream_t stream)
{
  const float* x        = (const float*)d_in[0];
  const float* f_in_w   = (const float*)d_in[1];
  const float* f_conv_w = (const float*)d_in[2];
  const float* f_conv_b = (const float*)d_in[3];
  const float* f_xproj  = (const float*)d_in[4];
  const float* f_dt_w   = (const float*)d_in[5];
  const float* f_dt_b   = (const float*)d_in[6];
  const float* f_A_log  = (const float*)d_in[7];
  const float* f_D      = (const float*)d_in[8];
  const float* f_out_w  = (const float*)d_in[9];
  const float* b_in_w   = (const float*)d_in[10];
  const float* b_conv_w = (const float*)d_in[11];
  const float* b_conv_b = (const float*)d_in[12];
  const float* b_xproj  = (const float*)d_in[13];
  const float* b_dt_w   = (const float*)d_in[14];
  const float* b_dt_b   = (const float*)d_in[15];
  const float* b_A_log  = (const float*)d_in[16];
  const float* b_D      = (const float*)d_in[17];
  const float* b_out_w  = (const float*)d_in[18];
  const float* ln1_g    = (const float*)d_in[19];
  const float* ln1_b    = (const float*)d_in[20];
  const float* ln2_g    = (const float*)d_in[21];
  const float* ln2_b    = (const float*)d_in[22];
  const float* ff_w1    = (const float*)d_in[23];
  const float* ff_b1    = (const float*)d_in[24];
  const float* ff_w2    = (const float*)d_in[25];
  const float* ff_b2    = (const float*)d_in[26];
  float* out = (float*)d_out;

  float* ws = (float*)d_ws;
  size_t o = 0;
  float* xn_f   = ws + o; o += (size_t)MR*DM;       // 3,145,728
  float* xn_r   = ws + o; o += (size_t)MR*DM;
  float* xz_f   = ws + o; o += (size_t)MR*2*DH;     // 12,582,912
  float* xz_b   = ws + o; o += (size_t)MR*2*DH;
  float* xh_f   = ws + o; o += (size_t)MR*DH;       // 6,291,456
  float* xh_b   = ws + o; o += (size_t)MR*DH;
  float* xdbl_f = ws + o; o += (size_t)MR*80;       // 327,680
  float* xdbl_b = ws + o; o += (size_t)MR*80;
  float* dtb_f  = ws + o; o += (size_t)MR*DH;
  float* dtb_b  = ws + o; o += (size_t)MR*DH;
  // aliases (lifetime-safe reuse)
  float* hend  = xn_f;   // NCHAN*NCH*NS = 3,145,728 floats == MR*DM exactly
  float* dtsum = xn_r;   // NCHAN*NCH = 196,608 floats (xn_r dead after in-proj; read only in p2)
  float* fo    = xn_r;   // written after dtsum's last read (scan p2)
  float* bo    = dtb_f;  // written after scan's last dt read
  float* mbuf  = xn_f;   // written after hend's last read (scan p3)
  float* ffh   = xz_f;   // written after z_f's last read (scan p3)

  // 1) LN1 (+ reversed copy)
  ln1_kernel<<<MR, 256, 0, stream>>>(x, ln1_g, ln1_b, xn_f, xn_r);
  // 2) in-proj for both directions (M=4096, N=3072, K=768)
  launch_gemm_big<128,0>(xn_f, DM, f_in_w, nullptr, xz_f, 2*DH, nullptr, MR, 2*DH, DM, stream);
  launch_gemm_big<128,0>(xn_r, DM, b_in_w, nullptr, xz_b, 2*DH, nullptr, MR, 2*DH, DM, stream);
  // 3) depthwise conv + SiLU
  conv_silu_kernel<<<(MR*DH)/256, 256, 0, stream>>>(xz_f, f_conv_w, f_conv_b, xh_f);
  conv_silu_kernel<<<(MR*DH)/256, 256, 0, stream>>>(xz_b, b_conv_w, b_conv_b, xh_b);
  // 4) x_dbl = xh @ xproj^T  (N=80)
  launch_gemm<0>(xh_f, DH, f_xproj, nullptr, xdbl_f, 80, nullptr, MR, 80, DH, stream);
  launch_gemm<0>(xh_b, DH, b_xproj, nullptr, xdbl_b, 80, nullptr, MR, 80, DH, stream);
  // 5) dt = softplus(dt_in @ dt_w^T + dt_b)   (K=48)
  launch_gemm<1>(xdbl_f, 80, f_dt_w, f_dt_b, dtb_f, DH, nullptr, MR, DH, RK, stream);
  launch_gemm<1>(xdbl_b, 80, b_dt_w, b_dt_b, dtb_b, DH, nullptr, MR, DH, RK, stream);
  // 6) chunked selective scan, both dirs; gated output in-place over xh
  scan_p1_kernel<<<4*NCH*NDBLK, 256, 0, stream>>>(
      dtb_f, xh_f, xdbl_f, f_A_log,
      dtb_b, xh_b, xdbl_b, b_A_log,
      hend, dtsum);
  scan_p2_kernel<<<(NCHAN*NS)/256, 256, 0, stream>>>(f_A_log, b_A_log, hend, dtsum);
  scan_p3_kernel<<<4*NCH*NDBLK, 256, 0, stream>>>(
      dtb_f, xh_f, xdbl_f, xz_f + DH, f_A_log, f_D, xh_f,
      dtb_b, xh_b, xdbl_b, xz_b + DH, b_A_log, b_D, xh_b,
      hend);
  // 7) out-proj per direction (M=4096, N=768, K=1536)
  launch_gemm_big<64,0>(xh_f, DH, f_out_w, nullptr, fo, DM, nullptr, MR, DM, DH, stream);
  launch_gemm_big<64,0>(xh_b, DH, b_out_w, nullptr, bo, DM, nullptr, MR, DM, DH, stream);
  // 8) LN2 of fo + reverse(bo)
  ln2_kernel<<<MR, 256, 0, stream>>>(fo, bo, ln2_g, ln2_b, mbuf);
  // 9) FFN
  launch_gemm_big<128,2>(mbuf, DM, ff_w1, ff_b1, ffh, 4*DM, nullptr, MR, 4*DM, DM, stream);
  launch_gemm_big<64,0>(ffh, 4*DM, ff_w2, ff_b2, out, DM, x, MR, DM, 4*DM, stream);
}

// Round 2
// 1709.219 us; speedup vs baseline: 1.4384x; 1.0866x over previous
//
#include <hip/hip_runtime.h>
#include <cstdint>
#include <cstddef>

#define BATCH_ 2
#define SEQ_ 2048
#define DM 768      // d_model
#define DH 1536     // d_inner
#define NS 16       // d_state
#define RK 48       // dt_rank
#define MR (BATCH_*SEQ_)   // 4096 rows
#define NCH 32      // scan chunks
#define CL (SEQ_/NCH)      // 64 steps per chunk
#define NCHAN (2*BATCH_*DH)        // 6144 (dir,b,d) channels
#define NDBLK (DH/256)             // 6 d-blocks per (dir,b,chunk)

__device__ __forceinline__ float sigmoidf_(float x){ return 1.f/(1.f+__expf(-x)); }

// ---------------- LayerNorm 1: writes xn and time-reversed xn ----------------
__global__ __launch_bounds__(256) void ln1_kernel(const float* __restrict__ x,
    const float* __restrict__ g, const float* __restrict__ bta,
    float* __restrict__ xn, float* __restrict__ xnr)
{
  int row = blockIdx.x;            // b*SEQ + l
  int tid = threadIdx.x;
  int bb = row >> 11, l = row & (SEQ_-1);
  __shared__ float s1[256], s2[256];
  float v[3]; float sum=0.f, sq=0.f;
  const float* xr = x + (size_t)row*DM;
  #pragma unroll
  for (int i=0;i<3;i++){ v[i] = xr[tid + i*256]; sum += v[i]; sq += v[i]*v[i]; }
  s1[tid]=sum; s2[tid]=sq; __syncthreads();
  for (int off=128; off>0; off>>=1){
    if (tid<off){ s1[tid]+=s1[tid+off]; s2[tid]+=s2[tid+off]; }
    __syncthreads();
  }
  float mean = s1[0] * (1.f/DM);
  float var  = s2[0] * (1.f/DM) - mean*mean;
  float rstd = rsqrtf(var + 1e-5f);
  size_t rrow = ((size_t)bb*SEQ_ + (SEQ_-1-l))*DM;
  #pragma unroll
  for (int i=0;i<3;i++){
    int c = tid + i*256;
    float val = (v[i]-mean)*rstd*g[c] + bta[c];
    xn[(size_t)row*DM + c] = val;
    xnr[rrow + c] = val;
  }
}

// ---------------- LayerNorm 2: m = LN(fo + reverse(bo)) ----------------
__global__ __launch_bounds__(256) void ln2_kernel(const float* __restrict__ fo,
    const float* __restrict__ bo, const float* __restrict__ g,
    const float* __restrict__ bta, float* __restrict__ m)
{
  int row = blockIdx.x;
  int tid = threadIdx.x;
  int bb = row >> 11, l = row & (SEQ_-1);
  __shared__ float s1[256], s2[256];
  size_t rrow = ((size_t)bb*SEQ_ + (SEQ_-1-l))*DM;
  float v[3]; float sum=0.f, sq=0.f;
  #pragma unroll
  for (int i=0;i<3;i++){
    int c = tid + i*256;
    v[i] = fo[(size_t)row*DM + c] + bo[rrow + c];
    sum += v[i]; sq += v[i]*v[i];
  }
  s1[tid]=sum; s2[tid]=sq; __syncthreads();
  for (int off=128; off>0; off>>=1){
    if (tid<off){ s1[tid]+=s1[tid+off]; s2[tid]+=s2[tid+off]; }
    __syncthreads();
  }
  float mean = s1[0] * (1.f/DM);
  float var  = s2[0] * (1.f/DM) - mean*mean;
  float rstd = rsqrtf(var + 1e-5f);
  #pragma unroll
  for (int i=0;i<3;i++){
    int c = tid + i*256;
    m[(size_t)row*DM + c] = (v[i]-mean)*rstd*g[c] + bta[c];
  }
}

// ---------------- small tiled GEMM (skinny N or K): C = act(A W^T + bias) ----
// ACT: 0=none, 1=softplus
template<int ACT>
__global__ __launch_bounds__(256) void gemm_nt(const float* __restrict__ A, int lda,
    const float* __restrict__ W, const float* __restrict__ bias,
    float* __restrict__ C, int ldc, const float* __restrict__ res,
    int M, int N, int K)
{
  __shared__ float As[16][64];
  __shared__ float Ws[16][64];
  int tid = threadIdx.x;
  int tx = tid & 15, ty = tid >> 4;
  int m0 = blockIdx.y * 64, n0 = blockIdx.x * 64;
  int lm = tid >> 2;          // 0..63
  int lk = (tid & 3) * 4;     // 0,4,8,12
  float acc[4][4] = {};
  for (int k0 = 0; k0 < K; k0 += 16) {
    float4 av = *(const float4*)(A + (size_t)(m0+lm)*lda + k0 + lk);
    As[lk+0][lm] = av.x; As[lk+1][lm] = av.y; As[lk+2][lm] = av.z; As[lk+3][lm] = av.w;
    int wn = n0 + lm;
    float4 wv = make_float4(0.f,0.f,0.f,0.f);
    if (wn < N) wv = *(const float4*)(W + (size_t)wn*K + k0 + lk);
    Ws[lk+0][lm] = wv.x; Ws[lk+1][lm] = wv.y; Ws[lk+2][lm] = wv.z; Ws[lk+3][lm] = wv.w;
    __syncthreads();
    #pragma unroll
    for (int k = 0; k < 16; ++k) {
      float4 a = *(const float4*)&As[k][ty*4];
      float4 w = *(const float4*)&Ws[k][tx*4];
      acc[0][0] += a.x*w.x; acc[0][1] += a.x*w.y; acc[0][2] += a.x*w.z; acc[0][3] += a.x*w.w;
      acc[1][0] += a.y*w.x; acc[1][1] += a.y*w.y; acc[1][2] += a.y*w.z; acc[1][3] += a.y*w.w;
      acc[2][0] += a.z*w.x; acc[2][1] += a.z*w.y; acc[2][2] += a.z*w.z; acc[2][3] += a.z*w.w;
      acc[3][0] += a.w*w.x; acc[3][1] += a.w*w.y; acc[3][2] += a.w*w.z; acc[3][3] += a.w*w.w;
    }
    __syncthreads();
  }
  #pragma unroll
  for (int i=0;i<4;i++){
    int row = m0 + ty*4 + i;
    #pragma unroll
    for (int j=0;j<4;j++){
      int col = n0 + tx*4 + j;
      if (col < N) {
        float vv = acc[i][j];
        if (bias) vv += bias[col];
        if (ACT == 1) vv = (vv > 20.f) ? vv : log1pf(expf(vv));            // softplus
        if (res) vv += res[(size_t)row*ldc + col];
        C[(size_t)row*ldc + col] = vv;
      }
    }
  }
}

// ---------------- big tiled GEMM: 128x128 tile, 8x8 microtile, pipelined ----
// Register-prefetch double-buffer: next tile's global loads are issued right
// after the read-barrier so they drain under the 1024-FMA compute phase.
// RAW=true: split-K partials -> C + blockIdx.z*M*N (no bias/act/res).
// Requires M%128==0, N%128==0, (Kc|K)%16==0.
template<int ACT, bool RAW>
__global__ __launch_bounds__(256) void gemm128(const float* __restrict__ A, int lda,
    const float* __restrict__ W, const float* __restrict__ bias,
    float* __restrict__ C, int ldc, const float* __restrict__ res,
    int M, int N, int K, int Kc)
{
  __shared__ float As[16][128];
  __shared__ float Ws[16][128];
  const int tid = threadIdx.x;
  const int m0 = blockIdx.y * 128, n0 = blockIdx.x * 128;
  const int tx = tid & 15, ty = tid >> 4;
  const int lr = tid >> 1, lk = (tid & 1) * 8;   // 2-way LDS stores (free)
  const float* Ap = A + (size_t)(m0 + lr) * lda + lk;
  const float* Wp = W + (size_t)(n0 + lr) * K + lk;
  const int kbeg = RAW ? blockIdx.z * Kc : 0;
  const int kend = RAW ? kbeg + Kc : K;

  float acc[8][8];
  #pragma unroll
  for (int i=0;i<8;i++)
    #pragma unroll
    for (int j=0;j<8;j++) acc[i][j] = 0.f;

  float4 a0 = *(const float4*)(Ap + kbeg);
  float4 a1 = *(const float4*)(Ap + kbeg + 4);
  float4 w0 = *(const float4*)(Wp + kbeg);
  float4 w1 = *(const float4*)(Wp + kbeg + 4);

  for (int k0 = kbeg; k0 < kend; k0 += 16) {
    __syncthreads();             // prev compute done reading LDS
    As[lk+0][lr]=a0.x; As[lk+1][lr]=a0.y; As[lk+2][lr]=a0.z; As[lk+3][lr]=a0.w;
    As[lk+4][lr]=a1.x; As[lk+5][lr]=a1.y; As[lk+6][lr]=a1.z; As[lk+7][lr]=a1.w;
    Ws[lk+0][lr]=w0.x; Ws[lk+1][lr]=w0.y; Ws[lk+2][lr]=w0.z; Ws[lk+3][lr]=w0.w;
    Ws[lk+4][lr]=w1.x; Ws[lk+5][lr]=w1.y; Ws[lk+6][lr]=w1.z; Ws[lk+7][lr]=w1.w;
    __syncthreads();
    if (k0 + 16 < kend) {        // issue next-tile loads; drain under compute
      a0 = *(const float4*)(Ap + k0 + 16);
      a1 = *(const float4*)(Ap + k0 + 20);
      w0 = *(const float4*)(Wp + k0 + 16);
      w1 = *(const float4*)(Wp + k0 + 20);
    }
    #pragma unroll
    for (int k = 0; k < 16; ++k) {
      float av[8], wv[8];
      *(float4*)&av[0] = *(const float4*)&As[k][ty*4];
      *(float4*)&av[4] = *(const float4*)&As[k][64 + ty*4];
      *(float4*)&wv[0] = *(const float4*)&Ws[k][tx*4];
      *(float4*)&wv[4] = *(const float4*)&Ws[k][64 + tx*4];
      #pragma unroll
      for (int i=0;i<8;i++)
        #pragma unroll
        for (int j=0;j<8;j++)
          acc[i][j] = fmaf(av[i], wv[j], acc[i][j]);
    }
  }

  if constexpr (RAW) {
    float* P = C + (size_t)blockIdx.z * ((size_t)M * N);
    #pragma unroll
    for (int i=0;i<8;i++){
      int row = m0 + ((i < 4) ? (ty*4 + i) : (64 + ty*4 + i - 4));
      #pragma unroll
      for (int jj=0;jj<2;jj++){
        int colb = n0 + jj*64 + tx*4;
        *(float4*)(P + (size_t)row*N + colb) =
            make_float4(acc[i][jj*4+0], acc[i][jj*4+1], acc[i][jj*4+2], acc[i][jj*4+3]);
      }
    }
  } else {
    #pragma unroll
    for (int i=0;i<8;i++){
      int row = m0 + ((i < 4) ? (ty*4 + i) : (64 + ty*4 + i - 4));
      #pragma unroll
      for (int jj=0;jj<2;jj++){
        int colb = n0 + jj*64 + tx*4;
        float vv[4];
        #pragma unroll
        for (int j=0;j<4;j++){
          float t = acc[i][jj*4 + j];
          if (bias) t += bias[colb + j];
          if constexpr (ACT == 2) t = 0.5f*t*(1.f + erff(t*0.70710678118654752f));
          if (res) t += res[(size_t)row*ldc + colb + j];
          vv[j] = t;
        }
        *(float4*)(C + (size_t)row*ldc + colb) = make_float4(vv[0],vv[1],vv[2],vv[3]);
      }
    }
  }
}

// ---------------- split-K reduce: C = sum_k P[k] (+bias) (+res) --------------
// Requires ldc == N (true for all uses) and elems % 1024 == 0.
__global__ __launch_bounds__(256) void reduce_split(const float* __restrict__ P,
    const float* __restrict__ bias, const float* __restrict__ res,
    float* __restrict__ C, int N, size_t elems, int nsplit)
{
  size_t i = ((size_t)blockIdx.x*256 + threadIdx.x)*4;
  float4 s = *(const float4*)(P + i);
  for (int k=1;k<nsplit;k++){
    float4 p = *(const float4*)(P + (size_t)k*elems + i);
    s.x+=p.x; s.y+=p.y; s.z+=p.z; s.w+=p.w;
  }
  if (bias){
    int col = (int)(i % (size_t)N);
    const float4 b = *(const float4*)(bias + col);
    s.x+=b.x; s.y+=b.y; s.z+=b.z; s.w+=b.w;
  }
  if (res){
    const float4 r = *(const float4*)(res + i);
    s.x+=r.x; s.y+=r.y; s.z+=r.z; s.w+=r.w;
  }
  *(float4*)(C + i) = s;
}

// ---------------- depthwise causal conv(4) + SiLU ----------------
__global__ __launch_bounds__(256) void conv_silu_kernel(const float* __restrict__ xz,
    const float* __restrict__ cw, const float* __restrict__ cb, float* __restrict__ xh)
{
  int idx = blockIdx.x*256 + threadIdx.x;   // over MR*DH
  int d = idx % DH;
  int row = idx / DH;
  int l = row & (SEQ_-1);
  const float* base = xz + (size_t)row*(2*DH) + d;
  float acc = cb[d];
  #pragma unroll
  for (int j=0;j<4;j++){
    int ll = l - 3 + j;
    if (ll >= 0) acc += cw[d*4+j] * base[(ptrdiff_t)(j-3)*(2*DH)];
  }
  xh[(size_t)row*DH + d] = acc * sigmoidf_(acc);
}

// ================= chunked selective scan, d-coalesced =================
// One THREAD per (dir,b,chunk,d): all 16 states in registers. Consecutive
// threads = consecutive d -> dt/xh/z/yg fully coalesced. B/C staged in LDS
// per chunk (broadcast reads). Block = 256 d's; grid = 4(db) x NCH x NDBLK.

// Phase 1: local scan from h=0 over CL steps -> hend[unit*NS+n], dtsum.
__global__ __launch_bounds__(256) void scan_p1_kernel(
    const float* __restrict__ dt0, const float* __restrict__ xh0, const float* __restrict__ xd0,
    const float* __restrict__ Al0,
    const float* __restrict__ dt1, const float* __restrict__ xh1, const float* __restrict__ xd1,
    const float* __restrict__ Al1,
    float* __restrict__ hend, float* __restrict__ dtsum)
{
  int tid = threadIdx.x;
  int bid = blockIdx.x;
  int dblk = bid % NDBLK;
  int t   = bid / NDBLK;          // db*NCH + c
  int c   = t & (NCH-1);
  int db  = t >> 5;               // dir*2 + b
  int dir = db >> 1, bb = db & 1;
  int d = dblk*256 + tid;
  const float* dt = dir ? dt1 : dt0;
  const float* xh = dir ? xh1 : xh0;
  const float* xd = dir ? xd1 : xd0;
  const float* Al = dir ? Al1 : Al0;

  __shared__ float sB[CL][NS];    // 4 KB
  {
    const float* xdb = xd + ((size_t)bb*SEQ_ + (size_t)c*CL)*80 + RK;
    int row = tid >> 2, part = tid & 3;   // 256 float4 = CL*NS floats
    *(float4*)&sB[row][part*4] = *(const float4*)(xdb + (size_t)row*80 + part*4);
  }
  float An[NS];
  {
    const float4* ap = (const float4*)(Al + (size_t)d*NS);
    #pragma unroll
    for (int q=0;q<4;q++){
      float4 a = ap[q];
      An[4*q+0] = -__expf(a.x); An[4*q+1] = -__expf(a.y);
      An[4*q+2] = -__expf(a.z); An[4*q+3] = -__expf(a.w);
    }
  }
  __syncthreads();

  float h[NS];
  #pragma unroll
  for (int n=0;n<NS;n++) h[n] = 0.f;
  float dts = 0.f;
  size_t base = ((size_t)bb*SEQ_ + (size_t)c*CL)*DH + d;
  #pragma unroll 4
  for (int l=0;l<CL;++l){
    float dtv = dt[base], uv = xh[base];
    float du = dtv*uv;
    float Bv[NS];
    *(float4*)&Bv[0]  = *(const float4*)&sB[l][0];
    *(float4*)&Bv[4]  = *(const float4*)&sB[l][4];
    *(float4*)&Bv[8]  = *(const float4*)&sB[l][8];
    *(float4*)&Bv[12] = *(const float4*)&sB[l][12];
    #pragma unroll
    for (int n=0;n<NS;n++)
      h[n] = h[n]*__expf(dtv*An[n]) + du*Bv[n];
    dts += dtv;
    base += DH;
  }
  size_t unit = ((size_t)db*DH + d)*NCH + c;
  float4* hp = (float4*)(hend + unit*NS);
  hp[0] = make_float4(h[0],h[1],h[2],h[3]);
  hp[1] = make_float4(h[4],h[5],h[6],h[7]);
  hp[2] = make_float4(h[8],h[9],h[10],h[11]);
  hp[3] = make_float4(h[12],h[13],h[14],h[15]);
  dtsum[(size_t)c*NCHAN + (size_t)db*DH + d] = dts;   // [c][ch] layout: coalesced
}

// Phase 2: per (channel, n): sequential over NCH chunks; hend -> hstart prefix.
__global__ __launch_bounds__(256) void scan_p2_kernel(
    const float* __restrict__ Al0, const float* __restrict__ Al1,
    float* __restrict__ hend, const float* __restrict__ dtsum)
{
  int t = blockIdx.x*256 + threadIdx.x;      // 0 .. NCHAN*NS-1
  int n = t & 15;
  int ch = t >> 4;
  int d  = ch % DH;
  int dir = (ch / DH) >> 1;
  const float* Al = dir ? Al1 : Al0;
  float An = -__expf(Al[d*NS + n]);
  float h0 = 0.f;
  size_t ub = (size_t)ch * NCH;
  #pragma unroll
  for (int c = 0; c < NCH; ++c) {
    float P  = __expf(An * dtsum[(size_t)c*NCHAN + ch]);
    float he = hend[(ub + c)*NS + n];
    hend[(ub + c)*NS + n] = h0;              // now holds hstart for chunk c
    h0 = h0 * P + he;
  }
}

// Phase 3: re-run recurrence from hstart, full output + gating, in-place over xh.
__global__ __launch_bounds__(256) void scan_p3_kernel(
    const float* __restrict__ dt0, const float* __restrict__ xh0, const float* __restrict__ xd0,
    const float* __restrict__ z0, const float* __restrict__ Al0, const float* __restrict__ Dp0,
    float* __restrict__ yg0,
    const float* __restrict__ dt1, const float* __restrict__ xh1, const float* __restrict__ xd1,
    const float* __restrict__ z1, const float* __restrict__ Al1, const float* __restrict__ Dp1,
    float* __restrict__ yg1,
    const float* __restrict__ hstart)
{
  int tid = threadIdx.x;
  int bid = blockIdx.x;
  int dblk = bid % NDBLK;
  int t   = bid / NDBLK;
  int c   = t & (NCH-1);
  int db  = t >> 5;
  int dir = db >> 1, bb = db & 1;
  int d = dblk*256 + tid;
  const float* dt = dir ? dt1 : dt0;
  const float* xh = dir ? xh1 : xh0;
  const float* xd = dir ? xd1 : xd0;
  const float* zp = dir ? z1  : z0;
  const float* Al = dir ? Al1 : Al0;
  const float* Dp = dir ? Dp1 : Dp0;
  float*       yg = dir ? yg1 : yg0;

  __shared__ float sBC[CL][2*NS];   // 8 KB
  {
    const float* xdb = xd + ((size_t)bb*SEQ_ + (size_t)c*CL)*80 + RK;
    #pragma unroll
    for (int i=0;i<2;i++){
      int idx = tid + i*256;        // 512 float4 = CL*2*NS floats
      int row = idx >> 3, part = idx & 7;
      *(float4*)&sBC[row][part*4] = *(const float4*)(xdb + (size_t)row*80 + part*4);
    }
  }
  float An[NS];
  {
    const float4* ap = (const float4*)(Al + (size_t)d*NS);
    #pragma unroll
    for (int q=0;q<4;q++){
      float4 a = ap[q];
      An[4*q+0] = -__expf(a.x); An[4*q+1] = -__expf(a.y);
      An[4*q+2] = -__expf(a.z); An[4*q+3] = -__expf(a.w);
    }
  }
  float Dd = Dp[d];
  __syncthreads();

  size_t unit = ((size_t)db*DH + d)*NCH + c;
  float h[NS];
  {
    const float4* hp = (const float4*)(hstart + unit*NS);
    float4 h0=hp[0], h1=hp[1], h2=hp[2], h3=hp[3];
    h[0]=h0.x; h[1]=h0.y; h[2]=h0.z; h[3]=h0.w;
    h[4]=h1.x; h[5]=h1.y; h[6]=h1.z; h[7]=h1.w;
    h[8]=h2.x; h[9]=h2.y; h[10]=h2.z; h[11]=h2.w;
    h[12]=h3.x; h[13]=h3.y; h[14]=h3.z; h[15]=h3.w;
  }
  size_t base = ((size_t)bb*SEQ_ + (size_t)c*CL)*DH + d;
  size_t zidx = ((size_t)bb*SEQ_ + (size_t)c*CL)*(size_t)(2*DH) + d;
  #pragma unroll 2
  for (int l=0;l<CL;++l){
    float dtv = dt[base], uv = xh[base];
    float zv = zp[zidx];
    float du = dtv*uv;
    float Bv[NS], Cv[NS];
    *(float4*)&Bv[0]  = *(const float4*)&sBC[l][0];
    *(float4*)&Bv[4]  = *(const float4*)&sBC[l][4];
    *(float4*)&Bv[8]  = *(const float4*)&sBC[l][8];
    *(float4*)&Bv[12] = *(const float4*)&sBC[l][12];
    *(float4*)&Cv[0]  = *(const float4*)&sBC[l][16];
    *(float4*)&Cv[4]  = *(const float4*)&sBC[l][20];
    *(float4*)&Cv[8]  = *(const float4*)&sBC[l][24];
    *(float4*)&Cv[12] = *(const float4*)&sBC[l][28];
    float y = 0.f;
    #pragma unroll
    for (int n=0;n<NS;n++){
      h[n] = h[n]*__expf(dtv*An[n]) + du*Bv[n];
      y = fmaf(h[n], Cv[n], y);
    }
    float yv = y + uv*Dd;
    yg[base] = yv * (zv * sigmoidf_(zv));
    base += DH; zidx += 2*DH;
  }
}

template<int ACT>
static inline void launch_gemm(const float* A, int lda, const float* W, const float* bias,
                               float* C, int ldc, const float* res,
                               int M, int N, int K, hipStream_t s)
{
  dim3 grid((N+63)/64, M/64);
  gemm_nt<ACT><<<grid, dim3(256), 0, s>>>(A, lda, W, bias, C, ldc, res, M, N, K);
}

template<int ACT>
static inline void launch_g128(const float* A, int lda, const float* W, const float* bias,
                               float* C, int ldc, const float* res,
                               int M, int N, int K, hipStream_t s)
{
  dim3 grid(N/128, M/128);
  gemm128<ACT,false><<<grid, dim3(256), 0, s>>>(A, lda, W, bias, C, ldc, res, M, N, K, 0);
}

static inline void launch_g128_split(const float* A, int lda, const float* W,
                                     float* P, int M, int N, int K, int nsplit,
                                     hipStream_t s)
{
  dim3 grid(N/128, M/128, nsplit);
  gemm128<0,true><<<grid, dim3(256), 0, s>>>(A, lda, W, nullptr, P, N, nullptr,
                                             M, N, K, K/nsplit);
}

extern "C" void kernel_launch(void* const* d_in, const int* in_sizes, int n_in,
                              void* d_out, int out_size, void* d_ws, size_t ws_size,
                              hipStream_t stream)
{
  const float* x        = (const float*)d_in[0];
  const float* f_in_w   = (const float*)d_in[1];
  const float* f_conv_w = (const float*)d_in[2];
  const float* f_conv_b = (const float*)d_in[3];
  const float* f_xproj  = (const float*)d_in[4];
  const float* f_dt_w   = (const float*)d_in[5];
  const float* f_dt_b   = (const float*)d_in[6];
  const float* f_A_log  = (const float*)d_in[7];
  const float* f_D      = (const float*)d_in[8];
  const float* f_out_w  = (const float*)d_in[9];
  const float* b_in_w   = (const float*)d_in[10];
  const float* b_conv_w = (const float*)d_in[11];
  const float* b_conv_b = (const float*)d_in[12];
  const float* b_xproj  = (const float*)d_in[13];
  const float* b_dt_w   = (const float*)d_in[14];
  const float* b_dt_b   = (const float*)d_in[15];
  const float* b_A_log  = (const float*)d_in[16];
  const float* b_D      = (const float*)d_in[17];
  const float* b_out_w  = (const float*)d_in[18];
  const float* ln1_g    = (const float*)d_in[19];
  const float* ln1_b    = (const float*)d_in[20];
  const float* ln2_g    = (const float*)d_in[21];
  const float* ln2_b    = (const float*)d_in[22];
  const float* ff_w1    = (const float*)d_in[23];
  const float* ff_b1    = (const float*)d_in[24];
  const float* ff_w2    = (const float*)d_in[25];
  const float* ff_b2    = (const float*)d_in[26];
  float* out = (float*)d_out;

  float* ws = (float*)d_ws;
  size_t o = 0;
  float* xn_f   = ws + o; o += (size_t)MR*DM;       // 3,145,728
  float* xn_r   = ws + o; o += (size_t)MR*DM;
  float* xz_f   = ws + o; o += (size_t)MR*2*DH;     // 12,582,912
  float* xz_b   = ws + o; o += (size_t)MR*2*DH;
  float* xh_f   = ws + o; o += (size_t)MR*DH;       // 6,291,456
  float* xh_b   = ws + o; o += (size_t)MR*DH;
  float* xdbl_f = ws + o; o += (size_t)MR*80;       // 327,680
  float* xdbl_b = ws + o; o += (size_t)MR*80;
  float* dtb_f  = ws + o; o += (size_t)MR*DH;
  float* dtb_b  = ws + o; o += (size_t)MR*DH;
  // aliases (lifetime-safe reuse)
  float* hend  = xn_f;   // NCHAN*NCH*NS = 3,145,728 floats == MR*DM exactly
  float* dtsum = xn_r;   // NCHAN*NCH = 196,608 floats (xn_r dead after in-proj; read only in p2)
  float* fo    = xn_r;   // written after dtsum's last read (scan p2)
  float* bo    = dtb_f;  // written after scan's last dt read (p3)
  float* mbuf  = xn_f;   // written after hend's last read (scan p3)
  float* ffh   = xz_f;   // written after out-proj partials' last read (reduce)
  float* part1 = xz_f;   // out-proj split-K partials: 4 * MR*DM = 12,582,912 == MR*2*DH
  float* part2 = xz_b;   // ff_w2 split-K partials (z_b dead after scan p3)
  const size_t EL = (size_t)MR*DM;   // 3,145,728 (partial-buffer stride)

  // 1) LN1 (+ reversed copy)
  ln1_kernel<<<MR, 256, 0, stream>>>(x, ln1_g, ln1_b, xn_f, xn_r);
  // 2) in-proj for both directions (M=4096, N=3072, K=768), pipelined 128x128
  launch_g128<0>(xn_f, DM, f_in_w, nullptr, xz_f, 2*DH, nullptr, MR, 2*DH, DM, stream);
  launch_g128<0>(xn_r, DM, b_in_w, nullptr, xz_b, 2*DH, nullptr, MR, 2*DH, DM, stream);
  // 3) depthwise conv + SiLU
  conv_silu_kernel<<<(MR*DH)/256, 256, 0, stream>>>(xz_f, f_conv_w, f_conv_b, xh_f);
  conv_silu_kernel<<<(MR*DH)/256, 256, 0, stream>>>(xz_b, b_conv_w, b_conv_b, xh_b);
  // 4) x_dbl = xh @ xproj^T  (N=80)
  launch_gemm<0>(xh_f, DH, f_xproj, nullptr, xdbl_f, 80, nullptr, MR, 80, DH, stream);
  launch_gemm<0>(xh_b, DH, b_xproj, nullptr, xdbl_b, 80, nullptr, MR, 80, DH, stream);
  // 5) dt = softplus(dt_in @ dt_w^T + dt_b)   (K=48)
  launch_gemm<1>(xdbl_f, 80, f_dt_w, f_dt_b, dtb_f, DH, nullptr, MR, DH, RK, stream);
  launch_gemm<1>(xdbl_b, 80, b_dt_w, b_dt_b, dtb_b, DH, nullptr, MR, DH, RK, stream);
  // 6) chunked selective scan, both dirs; gated output in-place over xh
  scan_p1_kernel<<<4*NCH*NDBLK, 256, 0, stream>>>(
      dtb_f, xh_f, xdbl_f, f_A_log,
      dtb_b, xh_b, xdbl_b, b_A_log,
      hend, dtsum);
  scan_p2_kernel<<<(NCHAN*NS)/256, 256, 0, stream>>>(f_A_log, b_A_log, hend, dtsum);
  scan_p3_kernel<<<4*NCH*NDBLK, 256, 0, stream>>>(
      dtb_f, xh_f, xdbl_f, xz_f + DH, f_A_log, f_D, xh_f,
      dtb_b, xh_b, xdbl_b, xz_b + DH, b_A_log, b_D, xh_b,
      hend);
  // 7) out-proj per direction (M=4096, N=768, K=1536): split-K x4 + reduce
  launch_g128_split(xh_f, DH, f_out_w, part1, MR, DM, DH, 4, stream);
  reduce_split<<<(int)(EL/1024), 256, 0, stream>>>(part1, nullptr, nullptr, fo, DM, EL, 4);
  launch_g128_split(xh_b, DH, b_out_w, part1, MR, DM, DH, 4, stream);
  reduce_split<<<(int)(EL/1024), 256, 0, stream>>>(part1, nullptr, nullptr, bo, DM, EL, 4);
  // 8) LN2 of fo + reverse(bo)
  ln2_kernel<<<MR, 256, 0, stream>>>(fo, bo, ln2_g, ln2_b, mbuf);
  // 9) FFN: w1 (N=3072, K=768) pipelined; w2 (N=768, K=3072) split-K x4 + reduce
  launch_g128<2>(mbuf, DM, ff_w1, ff_b1, ffh, 4*DM, nullptr, MR, 4*DM, DM, stream);
  launch_g128_split(ffh, 4*DM, ff_w2, part2, MR, DM, 4*DM, 4, stream);
  reduce_split<<<(int)(EL/1024), 256, 0, stream>>>(part2, ff_b2, x, out, DM, EL, 4);
}

// Round 3
// 1103.436 us; speedup vs baseline: 2.2282x; 1.5490x over previous
//
#include <hip/hip_runtime.h>
#include <cstdint>
#include <cstddef>

#define BATCH_ 2
#define SEQ_ 2048
#define DM 768      // d_model
#define DH 1536     // d_inner
#define NS 16       // d_state
#define RK 48       // dt_rank
#define MR (BATCH_*SEQ_)   // 4096 rows
#define NCH 32      // scan chunks
#define CL (SEQ_/NCH)      // 64 steps per chunk
#define NCHAN (2*BATCH_*DH)        // 6144 (dir,b,d) channels
#define NDBLK (DH/256)             // 6 d-blocks per (dir,b,chunk)

typedef __attribute__((ext_vector_type(8))) short short8b;   // 8 bf16 = 4 VGPR
typedef __attribute__((ext_vector_type(4))) float f32x4;

__device__ __forceinline__ float sigmoidf_(float x){ return 1.f/(1.f+__expf(-x)); }

// split fp32 -> bf16 hi (truncate) + bf16 lo (residual, truncate).
// a,b supply 8 consecutive k-values; element order identical for A and B
// (k-permutation invariance of MFMA makes exact slot->k mapping irrelevant).
__device__ __forceinline__ void split8(float4 a, float4 b, short8b& hi, short8b& lo){
  float xs[8] = {a.x,a.y,a.z,a.w,b.x,b.y,b.z,b.w};
  short8b h, l;
  #pragma unroll
  for (int e=0;e<8;e++){
    unsigned u = __float_as_uint(xs[e]);
    h[e] = (short)(u >> 16);
    float hf = __uint_as_float(u & 0xFFFF0000u);
    float lf = xs[e] - hf;              // exact
    l[e] = (short)(__float_as_uint(lf) >> 16);
  }
  hi = h; lo = l;
}

// ---------------- LayerNorm 1: writes xn and time-reversed xn ----------------
__global__ __launch_bounds__(256) void ln1_kernel(const float* __restrict__ x,
    const float* __restrict__ g, const float* __restrict__ bta,
    float* __restrict__ xn, float* __restrict__ xnr)
{
  int row = blockIdx.x;            // b*SEQ + l
  int tid = threadIdx.x;
  int bb = row >> 11, l = row & (SEQ_-1);
  __shared__ float s1[256], s2[256];
  float v[3]; float sum=0.f, sq=0.f;
  const float* xr = x + (size_t)row*DM;
  #pragma unroll
  for (int i=0;i<3;i++){ v[i] = xr[tid + i*256]; sum += v[i]; sq += v[i]*v[i]; }
  s1[tid]=sum; s2[tid]=sq; __syncthreads();
  for (int off=128; off>0; off>>=1){
    if (tid<off){ s1[tid]+=s1[tid+off]; s2[tid]+=s2[tid+off]; }
    __syncthreads();
  }
  float mean = s1[0] * (1.f/DM);
  float var  = s2[0] * (1.f/DM) - mean*mean;
  float rstd = rsqrtf(var + 1e-5f);
  size_t rrow = ((size_t)bb*SEQ_ + (SEQ_-1-l))*DM;
  #pragma unroll
  for (int i=0;i<3;i++){
    int c = tid + i*256;
    float val = (v[i]-mean)*rstd*g[c] + bta[c];
    xn[(size_t)row*DM + c] = val;
    xnr[rrow + c] = val;
  }
}

// ---------------- LayerNorm 2: m = LN(fo + reverse(bo)) ----------------
__global__ __launch_bounds__(256) void ln2_kernel(const float* __restrict__ fo,
    const float* __restrict__ bo, const float* __restrict__ g,
    const float* __restrict__ bta, float* __restrict__ m)
{
  int row = blockIdx.x;
  int tid = threadIdx.x;
  int bb = row >> 11, l = row & (SEQ_-1);
  __shared__ float s1[256], s2[256];
  size_t rrow = ((size_t)bb*SEQ_ + (SEQ_-1-l))*DM;
  float v[3]; float sum=0.f, sq=0.f;
  #pragma unroll
  for (int i=0;i<3;i++){
    int c = tid + i*256;
    v[i] = fo[(size_t)row*DM + c] + bo[rrow + c];
    sum += v[i]; sq += v[i]*v[i];
  }
  s1[tid]=sum; s2[tid]=sq; __syncthreads();
  for (int off=128; off>0; off>>=1){
    if (tid<off){ s1[tid]+=s1[tid+off]; s2[tid]+=s2[tid+off]; }
    __syncthreads();
  }
  float mean = s1[0] * (1.f/DM);
  float var  = s2[0] * (1.f/DM) - mean*mean;
  float rstd = rsqrtf(var + 1e-5f);
  #pragma unroll
  for (int i=0;i<3;i++){
    int c = tid + i*256;
    m[(size_t)row*DM + c] = (v[i]-mean)*rstd*g[c] + bta[c];
  }
}

// ---------------- small tiled GEMM (skinny N or K): C = act(A W^T + bias) ----
// ACT: 0=none, 1=softplus
template<int ACT>
__global__ __launch_bounds__(256) void gemm_nt(const float* __restrict__ A, int lda,
    const float* __restrict__ W, const float* __restrict__ bias,
    float* __restrict__ C, int ldc, const float* __restrict__ res,
    int M, int N, int K)
{
  __shared__ float As[16][64];
  __shared__ float Ws[16][64];
  int tid = threadIdx.x;
  int tx = tid & 15, ty = tid >> 4;
  int m0 = blockIdx.y * 64, n0 = blockIdx.x * 64;
  int lm = tid >> 2;          // 0..63
  int lk = (tid & 3) * 4;     // 0,4,8,12
  float acc[4][4] = {};
  for (int k0 = 0; k0 < K; k0 += 16) {
    float4 av = *(const float4*)(A + (size_t)(m0+lm)*lda + k0 + lk);
    As[lk+0][lm] = av.x; As[lk+1][lm] = av.y; As[lk+2][lm] = av.z; As[lk+3][lm] = av.w;
    int wn = n0 + lm;
    float4 wv = make_float4(0.f,0.f,0.f,0.f);
    if (wn < N) wv = *(const float4*)(W + (size_t)wn*K + k0 + lk);
    Ws[lk+0][lm] = wv.x; Ws[lk+1][lm] = wv.y; Ws[lk+2][lm] = wv.z; Ws[lk+3][lm] = wv.w;
    __syncthreads();
    #pragma unroll
    for (int k = 0; k < 16; ++k) {
      float4 a = *(const float4*)&As[k][ty*4];
      float4 w = *(const float4*)&Ws[k][tx*4];
      acc[0][0] += a.x*w.x; acc[0][1] += a.x*w.y; acc[0][2] += a.x*w.z; acc[0][3] += a.x*w.w;
      acc[1][0] += a.y*w.x; acc[1][1] += a.y*w.y; acc[1][2] += a.y*w.z; acc[1][3] += a.y*w.w;
      acc[2][0] += a.z*w.x; acc[2][1] += a.z*w.y; acc[2][2] += a.z*w.z; acc[2][3] += a.z*w.w;
      acc[3][0] += a.w*w.x; acc[3][1] += a.w*w.y; acc[3][2] += a.w*w.z; acc[3][3] += a.w*w.w;
    }
    __syncthreads();
  }
  #pragma unroll
  for (int i=0;i<4;i++){
    int row = m0 + ty*4 + i;
    #pragma unroll
    for (int j=0;j<4;j++){
      int col = n0 + tx*4 + j;
      if (col < N) {
        float vv = acc[i][j];
        if (bias) vv += bias[col];
        if (ACT == 1) vv = (vv > 20.f) ? vv : log1pf(expf(vv));            // softplus
        if (res) vv += res[(size_t)row*ldc + col];
        C[(size_t)row*ldc + col] = vv;
      }
    }
  }
}

// ============== MFMA GEMM: bf16 hi/lo split-compensated (fp32-class) ========
// 128x128 tile, BK=64, 4 waves each computing a 64x64 subtile as 4x4 frags of
// 16x16x32. 3 MFMA per fragment pair: ahi*bhi + ahi*blo + alo*bhi (rel err
// ~2^-16). fp32->bf16 hi/lo conversion fused into LDS staging; XOR-swizzled
// LDS (row = 128 B = 8x16B slots, slot ^= row&7) -> both ds_write_b128 and
// ds_read_b128 at the structural 8-cycle minimum. Register prefetch of the
// next K-tile issued under compute.
// RAW=true: split-K partials -> C + blockIdx.z*M*N. Requires M,N%128, K%64==0.
template<int ACT, bool RAW>
__global__ __launch_bounds__(256,2) void gemm_mfma(const float* __restrict__ A, int lda,
    const float* __restrict__ W, const float* __restrict__ bias,
    float* __restrict__ C, int ldc, const float* __restrict__ res,
    int M, int N, int K, int Kc)
{
  __shared__ short8b Ah[1024], Al_[1024], Bh[1024], Bl[1024];  // 4 x 16 KB
  const int tid = threadIdx.x;
  const int m0 = blockIdx.y*128, n0 = blockIdx.x*128;
  const int lane = tid & 63, wv = tid >> 6;
  const int wr = (wv>>1)*64, wc = (wv&1)*64;       // wave's 64x64 subtile
  const int li = lane & 15, lg = lane >> 4;
  const int sr = tid >> 1, sh = tid & 1;           // staging: row 0..127, k-half
  const int kbeg = RAW ? blockIdx.z*Kc : 0;
  const int nkt = (RAW ? Kc : K) >> 6;
  const float* Ap = A + (size_t)(m0+sr)*lda + kbeg + sh*32;
  const float* Wp = W + (size_t)(n0+sr)*K  + kbeg + sh*32;

  f32x4 acc[4][4];
  #pragma unroll
  for (int i=0;i<4;i++)
    #pragma unroll
    for (int j=0;j<4;j++) acc[i][j] = (f32x4){0.f,0.f,0.f,0.f};

  float4 ga[8], gw[8];
  #pragma unroll
  for (int q=0;q<8;q++){ ga[q]=*(const float4*)(Ap+q*4); gw[q]=*(const float4*)(Wp+q*4); }

  for (int kt=0; kt<nkt; ++kt){
    __syncthreads();                 // all waves done reading LDS (prev tile)
    #pragma unroll
    for (int p=0;p<4;p++){
      short8b hi, lo;
      split8(ga[2*p], ga[2*p+1], hi, lo);
      int sl = sr*8 + ((sh*4+p) ^ (sr&7));
      Ah[sl]=hi; Al_[sl]=lo;
      split8(gw[2*p], gw[2*p+1], hi, lo);
      Bh[sl]=hi; Bl[sl]=lo;
    }
    __syncthreads();
    if (kt+1 < nkt){                 // prefetch next tile; drains under MFMA
      const float* An = Ap + (size_t)(kt+1)*64;
      const float* Wn = Wp + (size_t)(kt+1)*64;
      #pragma unroll
      for (int q=0;q<8;q++){ ga[q]=*(const float4*)(An+q*4); gw[q]=*(const float4*)(Wn+q*4); }
    }
    #pragma unroll
    for (int ks=0;ks<2;ks++){
      short8b afh[4],afl[4],bfh[4],bfl[4];
      #pragma unroll
      for (int f=0; f<4; f++){
        int sl = (ks*4+lg) ^ (li&7);
        afh[f]=Ah[(wr+f*16+li)*8+sl]; afl[f]=Al_[(wr+f*16+li)*8+sl];
        bfh[f]=Bh[(wc+f*16+li)*8+sl]; bfl[f]=Bl[(wc+f*16+li)*8+sl];
      }
      #pragma unroll
      for (int fr=0;fr<4;fr++)
        #pragma unroll
        for (int fc=0;fc<4;fc++){
          acc[fr][fc]=__builtin_amdgcn_mfma_f32_16x16x32_bf16(afh[fr],bfh[fc],acc[fr][fc],0,0,0);
          acc[fr][fc]=__builtin_amdgcn_mfma_f32_16x16x32_bf16(afh[fr],bfl[fc],acc[fr][fc],0,0,0);
          acc[fr][fc]=__builtin_amdgcn_mfma_f32_16x16x32_bf16(afl[fr],bfh[fc],acc[fr][fc],0,0,0);
        }
    }
  }

  // C/D layout (m89-verified): col = lane&15, row = (lane>>4)*4 + reg
  if constexpr (RAW){
    float* P = C + (size_t)blockIdx.z*((size_t)M*N);
    #pragma unroll
    for (int fr=0;fr<4;fr++)
      #pragma unroll
      for (int fc=0;fc<4;fc++){
        int col = n0 + wc + fc*16 + li;
        int row = m0 + wr + fr*16 + lg*4;
        #pragma unroll
        for (int rg=0;rg<4;rg++)
          P[(size_t)(row+rg)*N + col] = acc[fr][fc][rg];
      }
  } else {
    #pragma unroll
    for (int fr=0;fr<4;fr++)
      #pragma unroll
      for (int fc=0;fc<4;fc++){
        int col = n0 + wc + fc*16 + li;
        int row = m0 + wr + fr*16 + lg*4;
        float bv = bias ? bias[col] : 0.f;
        #pragma unroll
        for (int rg=0;rg<4;rg++){
          float t = acc[fr][fc][rg] + bv;
          if constexpr (ACT==2) t = 0.5f*t*(1.f+erff(t*0.70710678118654752f));
          if (res) t += res[(size_t)(row+rg)*ldc + col];
          C[(size_t)(row+rg)*ldc + col] = t;
        }
      }
  }
}

// ---------------- split-K reduce: C = sum_k P[k] (+bias) (+res) --------------
__global__ __launch_bounds__(256) void reduce_split(const float* __restrict__ P,
    const float* __restrict__ bias, const float* __restrict__ res,
    float* __restrict__ C, int N, size_t elems, int nsplit)
{
  size_t i = ((size_t)blockIdx.x*256 + threadIdx.x)*4;
  float4 s = *(const float4*)(P + i);
  for (int k=1;k<nsplit;k++){
    float4 p = *(const float4*)(P + (size_t)k*elems + i);
    s.x+=p.x; s.y+=p.y; s.z+=p.z; s.w+=p.w;
  }
  if (bias){
    int col = (int)(i % (size_t)N);
    const float4 b = *(const float4*)(bias + col);
    s.x+=b.x; s.y+=b.y; s.z+=b.z; s.w+=b.w;
  }
  if (res){
    const float4 r = *(const float4*)(res + i);
    s.x+=r.x; s.y+=r.y; s.z+=r.z; s.w+=r.w;
  }
  *(float4*)(C + i) = s;
}

// ---------------- depthwise causal conv(4) + SiLU ----------------
__global__ __launch_bounds__(256) void conv_silu_kernel(const float* __restrict__ xz,
    const float* __restrict__ cw, const float* __restrict__ cb, float* __restrict__ xh)
{
  int idx = blockIdx.x*256 + threadIdx.x;   // over MR*DH
  int d = idx % DH;
  int row = idx / DH;
  int l = row & (SEQ_-1);
  const float* base = xz + (size_t)row*(2*DH) + d;
  float acc = cb[d];
  #pragma unroll
  for (int j=0;j<4;j++){
    int ll = l - 3 + j;
    if (ll >= 0) acc += cw[d*4+j] * base[(ptrdiff_t)(j-3)*(2*DH)];
  }
  xh[(size_t)row*DH + d] = acc * sigmoidf_(acc);
}

// ================= chunked selective scan, d-coalesced =================
// Phase 1: local scan from h=0 over CL steps -> hend[unit*NS+n], dtsum.
__global__ __launch_bounds__(256) void scan_p1_kernel(
    const float* __restrict__ dt0, const float* __restrict__ xh0, const float* __restrict__ xd0,
    const float* __restrict__ Al0,
    const float* __restrict__ dt1, const float* __restrict__ xh1, const float* __restrict__ xd1,
    const float* __restrict__ Al1,
    float* __restrict__ hend, float* __restrict__ dtsum)
{
  int tid = threadIdx.x;
  int bid = blockIdx.x;
  int dblk = bid % NDBLK;
  int t   = bid / NDBLK;          // db*NCH + c
  int c   = t & (NCH-1);
  int db  = t >> 5;               // dir*2 + b
  int dir = db >> 1, bb = db & 1;
  int d = dblk*256 + tid;
  const float* dt = dir ? dt1 : dt0;
  const float* xh = dir ? xh1 : xh0;
  const float* xd = dir ? xd1 : xd0;
  const float* Al = dir ? Al1 : Al0;

  __shared__ float sB[CL][NS];    // 4 KB
  {
    const float* xdb = xd + ((size_t)bb*SEQ_ + (size_t)c*CL)*80 + RK;
    int row = tid >> 2, part = tid & 3;   // 256 float4 = CL*NS floats
    *(float4*)&sB[row][part*4] = *(const float4*)(xdb + (size_t)row*80 + part*4);
  }
  float An[NS];
  {
    const float4* ap = (const float4*)(Al + (size_t)d*NS);
    #pragma unroll
    for (int q=0;q<4;q++){
      float4 a = ap[q];
      An[4*q+0] = -__expf(a.x); An[4*q+1] = -__expf(a.y);
      An[4*q+2] = -__expf(a.z); An[4*q+3] = -__expf(a.w);
    }
  }
  __syncthreads();

  float h[NS];
  #pragma unroll
  for (int n=0;n<NS;n++) h[n] = 0.f;
  float dts = 0.f;
  size_t base = ((size_t)bb*SEQ_ + (size_t)c*CL)*DH + d;
  #pragma unroll 4
  for (int l=0;l<CL;++l){
    float dtv = dt[base], uv = xh[base];
    float du = dtv*uv;
    float Bv[NS];
    *(float4*)&Bv[0]  = *(const float4*)&sB[l][0];
    *(float4*)&Bv[4]  = *(const float4*)&sB[l][4];
    *(float4*)&Bv[8]  = *(const float4*)&sB[l][8];
    *(float4*)&Bv[12] = *(const float4*)&sB[l][12];
    #pragma unroll
    for (int n=0;n<NS;n++)
      h[n] = h[n]*__expf(dtv*An[n]) + du*Bv[n];
    dts += dtv;
    base += DH;
  }
  size_t unit = ((size_t)db*DH + d)*NCH + c;
  float4* hp = (float4*)(hend + unit*NS);
  hp[0] = make_float4(h[0],h[1],h[2],h[3]);
  hp[1] = make_float4(h[4],h[5],h[6],h[7]);
  hp[2] = make_float4(h[8],h[9],h[10],h[11]);
  hp[3] = make_float4(h[12],h[13],h[14],h[15]);
  dtsum[(size_t)c*NCHAN + (size_t)db*DH + d] = dts;   // [c][ch] layout: coalesced
}

// Phase 2: per (channel, n): sequential over NCH chunks; hend -> hstart prefix.
__global__ __launch_bounds__(256) void scan_p2_kernel(
    const float* __restrict__ Al0, const float* __restrict__ Al1,
    float* __restrict__ hend, const float* __restrict__ dtsum)
{
  int t = blockIdx.x*256 + threadIdx.x;      // 0 .. NCHAN*NS-1
  int n = t & 15;
  int ch = t >> 4;
  int d  = ch % DH;
  int dir = (ch / DH) >> 1;
  const float* Al = dir ? Al1 : Al0;
  float An = -__expf(Al[d*NS + n]);
  float h0 = 0.f;
  size_t ub = (size_t)ch * NCH;
  #pragma unroll
  for (int c = 0; c < NCH; ++c) {
    float P  = __expf(An * dtsum[(size_t)c*NCHAN + ch]);
    float he = hend[(ub + c)*NS + n];
    hend[(ub + c)*NS + n] = h0;              // now holds hstart for chunk c
    h0 = h0 * P + he;
  }
}

// Phase 3: re-run recurrence from hstart, full output + gating, in-place over xh.
__global__ __launch_bounds__(256) void scan_p3_kernel(
    const float* __restrict__ dt0, const float* __restrict__ xh0, const float* __restrict__ xd0,
    const float* __restrict__ z0, const float* __restrict__ Al0, const float* __restrict__ Dp0,
    float* __restrict__ yg0,
    const float* __restrict__ dt1, const float* __restrict__ xh1, const float* __restrict__ xd1,
    const float* __restrict__ z1, const float* __restrict__ Al1, const float* __restrict__ Dp1,
    float* __restrict__ yg1,
    const float* __restrict__ hstart)
{
  int tid = threadIdx.x;
  int bid = blockIdx.x;
  int dblk = bid % NDBLK;
  int t   = bid / NDBLK;
  int c   = t & (NCH-1);
  int db  = t >> 5;
  int dir = db >> 1, bb = db & 1;
  int d = dblk*256 + tid;
  const float* dt = dir ? dt1 : dt0;
  const float* xh = dir ? xh1 : xh0;
  const float* xd = dir ? xd1 : xd0;
  const float* zp = dir ? z1  : z0;
  const float* Al = dir ? Al1 : Al0;
  const float* Dp = dir ? Dp1 : Dp0;
  float*       yg = dir ? yg1 : yg0;

  __shared__ float sBC[CL][2*NS];   // 8 KB
  {
    const float* xdb = xd + ((size_t)bb*SEQ_ + (size_t)c*CL)*80 + RK;
    #pragma unroll
    for (int i=0;i<2;i++){
      int idx = tid + i*256;        // 512 float4 = CL*2*NS floats
      int row = idx >> 3, part = idx & 7;
      *(float4*)&sBC[row][part*4] = *(const float4*)(xdb + (size_t)row*80 + part*4);
    }
  }
  float An[NS];
  {
    const float4* ap = (const float4*)(Al + (size_t)d*NS);
    #pragma unroll
    for (int q=0;q<4;q++){
      float4 a = ap[q];
      An[4*q+0] = -__expf(a.x); An[4*q+1] = -__expf(a.y);
      An[4*q+2] = -__expf(a.z); An[4*q+3] = -__expf(a.w);
    }
  }
  float Dd = Dp[d];
  __syncthreads();

  size_t unit = ((size_t)db*DH + d)*NCH + c;
  float h[NS];
  {
    const float4* hp = (const float4*)(hstart + unit*NS);
    float4 h0=hp[0], h1=hp[1], h2=hp[2], h3=hp[3];
    h[0]=h0.x; h[1]=h0.y; h[2]=h0.z; h[3]=h0.w;
    h[4]=h1.x; h[5]=h1.y; h[6]=h1.z; h[7]=h1.w;
    h[8]=h2.x; h[9]=h2.y; h[10]=h2.z; h[11]=h2.w;
    h[12]=h3.x; h[13]=h3.y; h[14]=h3.z; h[15]=h3.w;
  }
  size_t base = ((size_t)bb*SEQ_ + (size_t)c*CL)*DH + d;
  size_t zidx = ((size_t)bb*SEQ_ + (size_t)c*CL)*(size_t)(2*DH) + d;
  #pragma unroll 2
  for (int l=0;l<CL;++l){
    float dtv = dt[base], uv = xh[base];
    float zv = zp[zidx];
    float du = dtv*uv;
    float Bv[NS], Cv[NS];
    *(float4*)&Bv[0]  = *(const float4*)&sBC[l][0];
    *(float4*)&Bv[4]  = *(const float4*)&sBC[l][4];
    *(float4*)&Bv[8]  = *(const float4*)&sBC[l][8];
    *(float4*)&Bv[12] = *(const float4*)&sBC[l][12];
    *(float4*)&Cv[0]  = *(const float4*)&sBC[l][16];
    *(float4*)&Cv[4]  = *(const float4*)&sBC[l][20];
    *(float4*)&Cv[8]  = *(const float4*)&sBC[l][24];
    *(float4*)&Cv[12] = *(const float4*)&sBC[l][28];
    float y = 0.f;
    #pragma unroll
    for (int n=0;n<NS;n++){
      h[n] = h[n]*__expf(dtv*An[n]) + du*Bv[n];
      y = fmaf(h[n], Cv[n], y);
    }
    float yv = y + uv*Dd;
    yg[base] = yv * (zv * sigmoidf_(zv));
    base += DH; zidx += 2*DH;
  }
}

template<int ACT>
static inline void launch_gemm(const float* A, int lda, const float* W, const float* bias,
                               float* C, int ldc, const float* res,
                               int M, int N, int K, hipStream_t s)
{
  dim3 grid((N+63)/64, M/64);
  gemm_nt<ACT><<<grid, dim3(256), 0, s>>>(A, lda, W, bias, C, ldc, res, M, N, K);
}

template<int ACT>
static inline void launch_mfma(const float* A, int lda, const float* W, const float* bias,
                               float* C, int ldc, const float* res,
                               int M, int N, int K, hipStream_t s)
{
  dim3 grid(N/128, M/128);
  gemm_mfma<ACT,false><<<grid, dim3(256), 0, s>>>(A, lda, W, bias, C, ldc, res, M, N, K, 0);
}

static inline void launch_mfma_split(const float* A, int lda, const float* W,
                                     float* P, int M, int N, int K, int nsplit,
                                     hipStream_t s)
{
  dim3 grid(N/128, M/128, nsplit);
  gemm_mfma<0,true><<<grid, dim3(256), 0, s>>>(A, lda, W, nullptr, P, N, nullptr,
                                               M, N, K, K/nsplit);
}

extern "C" void kernel_launch(void* const* d_in, const int* in_sizes, int n_in,
                              void* d_out, int out_size, void* d_ws, size_t ws_size,
                              hipStream_t stream)
{
  const float* x        = (const float*)d_in[0];
  const float* f_in_w   = (const float*)d_in[1];
  const float* f_conv_w = (const float*)d_in[2];
  const float* f_conv_b = (const float*)d_in[3];
  const float* f_xproj  = (const float*)d_in[4];
  const float* f_dt_w   = (const float*)d_in[5];
  const float* f_dt_b   = (const float*)d_in[6];
  const float* f_A_log  = (const float*)d_in[7];
  const float* f_D      = (const float*)d_in[8];
  const float* f_out_w  = (const float*)d_in[9];
  const float* b_in_w   = (const float*)d_in[10];
  const float* b_conv_w = (const float*)d_in[11];
  const float* b_conv_b = (const float*)d_in[12];
  const float* b_xproj  = (const float*)d_in[13];
  const float* b_dt_w   = (const float*)d_in[14];
  const float* b_dt_b   = (const float*)d_in[15];
  const float* b_A_log  = (const float*)d_in[16];
  const float* b_D      = (const float*)d_in[17];
  const float* b_out_w  = (const float*)d_in[18];
  const float* ln1_g    = (const float*)d_in[19];
  const float* ln1_b    = (const float*)d_in[20];
  const float* ln2_g    = (const float*)d_in[21];
  const float* ln2_b    = (const float*)d_in[22];
  const float* ff_w1    = (const float*)d_in[23];
  const float* ff_b1    = (const float*)d_in[24];
  const float* ff_w2    = (const float*)d_in[25];
  const float* ff_b2    = (const float*)d_in[26];
  float* out = (float*)d_out;

  float* ws = (float*)d_ws;
  size_t o = 0;
  float* xn_f   = ws + o; o += (size_t)MR*DM;       // 3,145,728
  float* xn_r   = ws + o; o += (size_t)MR*DM;
  float* xz_f   = ws + o; o += (size_t)MR*2*DH;     // 12,582,912
  float* xz_b   = ws + o; o += (size_t)MR*2*DH;
  float* xh_f   = ws + o; o += (size_t)MR*DH;       // 6,291,456
  float* xh_b   = ws + o; o += (size_t)MR*DH;
  float* xdbl_f = ws + o; o += (size_t)MR*80;       // 327,680
  float* xdbl_b = ws + o; o += (size_t)MR*80;
  float* dtb_f  = ws + o; o += (size_t)MR*DH;
  float* dtb_b  = ws + o; o += (size_t)MR*DH;
  // aliases (lifetime-safe reuse)
  float* hend  = xn_f;   // NCHAN*NCH*NS = 3,145,728 floats == MR*DM exactly
  float* dtsum = xn_r;   // NCHAN*NCH floats (xn_r dead after in-proj; read only in p2)
  float* fo    = xn_r;   // written after dtsum's last read (scan p2)
  float* bo    = dtb_f;  // written after scan's last dt read (p3)
  float* mbuf  = xn_f;   // written after hend's last read (scan p3)
  float* ffh   = xz_f;   // written after out-proj partials' last read (reduce)
  float* part1 = xz_f;   // out-proj split-K partials: 2 * MR*DM <= MR*2*DH
  float* part2 = xz_b;   // ff_w2 split-K partials (z_b dead after scan p3)
  const size_t EL = (size_t)MR*DM;   // 3,145,728 (partial-buffer stride)

  // 1) LN1 (+ reversed copy)
  ln1_kernel<<<MR, 256, 0, stream>>>(x, ln1_g, ln1_b, xn_f, xn_r);
  // 2) in-proj both dirs (M=4096, N=3072, K=768), MFMA bf16x3
  launch_mfma<0>(xn_f, DM, f_in_w, nullptr, xz_f, 2*DH, nullptr, MR, 2*DH, DM, stream);
  launch_mfma<0>(xn_r, DM, b_in_w, nullptr, xz_b, 2*DH, nullptr, MR, 2*DH, DM, stream);
  // 3) depthwise conv + SiLU
  conv_silu_kernel<<<(MR*DH)/256, 256, 0, stream>>>(xz_f, f_conv_w, f_conv_b, xh_f);
  conv_silu_kernel<<<(MR*DH)/256, 256, 0, stream>>>(xz_b, b_conv_w, b_conv_b, xh_b);
  // 4) x_dbl = xh @ xproj^T  (N=80) — skinny, fp32
  launch_gemm<0>(xh_f, DH, f_xproj, nullptr, xdbl_f, 80, nullptr, MR, 80, DH, stream);
  launch_gemm<0>(xh_b, DH, b_xproj, nullptr, xdbl_b, 80, nullptr, MR, 80, DH, stream);
  // 5) dt = softplus(dt_in @ dt_w^T + dt_b)   (K=48) — skinny, fp32
  launch_gemm<1>(xdbl_f, 80, f_dt_w, f_dt_b, dtb_f, DH, nullptr, MR, DH, RK, stream);
  launch_gemm<1>(xdbl_b, 80, b_dt_w, b_dt_b, dtb_b, DH, nullptr, MR, DH, RK, stream);
  // 6) chunked selective scan, both dirs; gated output in-place over xh
  scan_p1_kernel<<<4*NCH*NDBLK, 256, 0, stream>>>(
      dtb_f, xh_f, xdbl_f, f_A_log,
      dtb_b, xh_b, xdbl_b, b_A_log,
      hend, dtsum);
  scan_p2_kernel<<<(NCHAN*NS)/256, 256, 0, stream>>>(f_A_log, b_A_log, hend, dtsum);
  scan_p3_kernel<<<4*NCH*NDBLK, 256, 0, stream>>>(
      dtb_f, xh_f, xdbl_f, xz_f + DH, f_A_log, f_D, xh_f,
      dtb_b, xh_b, xdbl_b, xz_b + DH, b_A_log, b_D, xh_b,
      hend);
  // 7) out-proj per direction (M=4096, N=768, K=1536): MFMA split-K x2 + reduce
  launch_mfma_split(xh_f, DH, f_out_w, part1, MR, DM, DH, 2, stream);
  reduce_split<<<(int)(EL/1024), 256, 0, stream>>>(part1, nullptr, nullptr, fo, DM, EL, 2);
  launch_mfma_split(xh_b, DH, b_out_w, part1, MR, DM, DH, 2, stream);
  reduce_split<<<(int)(EL/1024), 256, 0, stream>>>(part1, nullptr, nullptr, bo, DM, EL, 2);
  // 8) LN2 of fo + reverse(bo)
  ln2_kernel<<<MR, 256, 0, stream>>>(fo, bo, ln2_g, ln2_b, mbuf);
  // 9) FFN: w1 (N=3072, K=768) MFMA + gelu; w2 (N=768, K=3072) MFMA split-K x2
  launch_mfma<2>(mbuf, DM, ff_w1, ff_b1, ffh, 4*DM, nullptr, MR, 4*DM, DM, stream);
  launch_mfma_split(ffh, 4*DM, ff_w2, part2, MR, DM, 4*DM, 2, stream);
  reduce_split<<<(int)(EL/1024), 256, 0, stream>>>(part2, ff_b2, x, out, DM, EL, 2);
}

// Round 5
// 966.000 us; speedup vs baseline: 2.5452x; 1.1423x over previous
//
#include <hip/hip_runtime.h>
#include <cstdint>
#include <cstddef>

#define BATCH_ 2
#define SEQ_ 2048
#define DM 768      // d_model
#define DH 1536     // d_inner
#define NS 16       // d_state
#define RK 48       // dt_rank
#define MR (BATCH_*SEQ_)   // 4096 rows
#define NCH 32      // scan chunks
#define CL (SEQ_/NCH)      // 64 steps per chunk
#define NCHAN (2*BATCH_*DH)        // 6144 (dir,b,d) channels
#define NDBLK (DH/256)             // 6 d-blocks per (dir,b,chunk)

typedef __attribute__((ext_vector_type(8))) short short8b;   // 8 bf16 = 4 VGPR
typedef __attribute__((ext_vector_type(4))) float f32x4;

__device__ __forceinline__ float sigmoidf_(float x){ return 1.f/(1.f+__expf(-x)); }

// fp32 -> bf16 hi (truncate) + bf16 lo (residual, truncate). rel err ~2^-16.
__device__ __forceinline__ void split1(float x, ushort& h, ushort& l){
  unsigned u = __float_as_uint(x);
  h = (ushort)(u >> 16);
  float lf = x - __uint_as_float(u & 0xFFFF0000u);   // exact
  l = (ushort)(__float_as_uint(lf) >> 16);
}

// ---------------- one-time weight split: fp32 -> bf16 hi/lo ------------------
__global__ __launch_bounds__(256) void split_kernel(const float* __restrict__ in,
    ushort* __restrict__ hi, ushort* __restrict__ lo, int n4)
{
  int i = blockIdx.x*256 + threadIdx.x;
  if (i >= n4) return;
  float4 v = ((const float4*)in)[i];
  ushort h0,h1,h2,h3,l0,l1,l2,l3;
  split1(v.x,h0,l0); split1(v.y,h1,l1); split1(v.z,h2,l2); split1(v.w,h3,l3);
  ((ushort4*)hi)[i] = make_ushort4(h0,h1,h2,h3);
  ((ushort4*)lo)[i] = make_ushort4(l0,l1,l2,l3);
}

// ------------- LayerNorm 1 -> bf16 hi/lo xn ---------------------------------
__global__ __launch_bounds__(256) void ln1_kernel(const float* __restrict__ x,
    const float* __restrict__ g, const float* __restrict__ bta,
    ushort* __restrict__ xnh, ushort* __restrict__ xnl)
{
  int row = blockIdx.x;            // b*SEQ + l
  int tid = threadIdx.x;
  __shared__ float s1[256], s2[256];
  float v[3]; float sum=0.f, sq=0.f;
  const float* xr = x + (size_t)row*DM;
  #pragma unroll
  for (int i=0;i<3;i++){ v[i] = xr[tid + i*256]; sum += v[i]; sq += v[i]*v[i]; }
  s1[tid]=sum; s2[tid]=sq; __syncthreads();
  for (int off=128; off>0; off>>=1){
    if (tid<off){ s1[tid]+=s1[tid+off]; s2[tid]+=s2[tid+off]; }
    __syncthreads();
  }
  float mean = s1[0] * (1.f/DM);
  float var  = s2[0] * (1.f/DM) - mean*mean;
  float rstd = rsqrtf(var + 1e-5f);
  #pragma unroll
  for (int i=0;i<3;i++){
    int c = tid + i*256;
    float val = (v[i]-mean)*rstd*g[c] + bta[c];
    ushort h, lo_;
    split1(val, h, lo_);
    xnh[(size_t)row*DM + c] = h;  xnl[(size_t)row*DM + c] = lo_;
  }
}

// ------------- LayerNorm 2: m = LN(fo + reverse(bo)) -> bf16 hi/lo ----------
__global__ __launch_bounds__(256) void ln2_kernel(const float* __restrict__ fo,
    const float* __restrict__ bo, const float* __restrict__ g,
    const float* __restrict__ bta, ushort* __restrict__ mh, ushort* __restrict__ ml)
{
  int row = blockIdx.x;
  int tid = threadIdx.x;
  int bb = row >> 11, l = row & (SEQ_-1);
  __shared__ float s1[256], s2[256];
  size_t rrow = ((size_t)bb*SEQ_ + (SEQ_-1-l))*DM;
  float v[3]; float sum=0.f, sq=0.f;
  #pragma unroll
  for (int i=0;i<3;i++){
    int c = tid + i*256;
    v[i] = fo[(size_t)row*DM + c] + bo[rrow + c];
    sum += v[i]; sq += v[i]*v[i];
  }
  s1[tid]=sum; s2[tid]=sq; __syncthreads();
  for (int off=128; off>0; off>>=1){
    if (tid<off){ s1[tid]+=s1[tid+off]; s2[tid]+=s2[tid+off]; }
    __syncthreads();
  }
  float mean = s1[0] * (1.f/DM);
  float var  = s2[0] * (1.f/DM) - mean*mean;
  float rstd = rsqrtf(var + 1e-5f);
  #pragma unroll
  for (int i=0;i<3;i++){
    int c = tid + i*256;
    float val = (v[i]-mean)*rstd*g[c] + bta[c];
    ushort h, lo_;
    split1(val, h, lo_);
    mh[(size_t)row*DM + c] = h;  ml[(size_t)row*DM + c] = lo_;
  }
}

// ---------------- small tiled GEMM (skinny N or K), fp32 --------------------
// ACT: 0=none, 1=softplus
template<int ACT>
__global__ __launch_bounds__(256) void gemm_nt(const float* __restrict__ A, int lda,
    const float* __restrict__ W, const float* __restrict__ bias,
    float* __restrict__ C, int ldc, const float* __restrict__ res,
    int M, int N, int K)
{
  __shared__ float As[16][64];
  __shared__ float Ws[16][64];
  int tid = threadIdx.x;
  int tx = tid & 15, ty = tid >> 4;
  int m0 = blockIdx.y * 64, n0 = blockIdx.x * 64;
  int lm = tid >> 2;          // 0..63
  int lk = (tid & 3) * 4;     // 0,4,8,12
  float acc[4][4] = {};
  for (int k0 = 0; k0 < K; k0 += 16) {
    float4 av = *(const float4*)(A + (size_t)(m0+lm)*lda + k0 + lk);
    As[lk+0][lm] = av.x; As[lk+1][lm] = av.y; As[lk+2][lm] = av.z; As[lk+3][lm] = av.w;
    int wn = n0 + lm;
    float4 wv = make_float4(0.f,0.f,0.f,0.f);
    if (wn < N) wv = *(const float4*)(W + (size_t)wn*K + k0 + lk);
    Ws[lk+0][lm] = wv.x; Ws[lk+1][lm] = wv.y; Ws[lk+2][lm] = wv.z; Ws[lk+3][lm] = wv.w;
    __syncthreads();
    #pragma unroll
    for (int k = 0; k < 16; ++k) {
      float4 a = *(const float4*)&As[k][ty*4];
      float4 w = *(const float4*)&Ws[k][tx*4];
      acc[0][0] += a.x*w.x; acc[0][1] += a.x*w.y; acc[0][2] += a.x*w.z; acc[0][3] += a.x*w.w;
      acc[1][0] += a.y*w.x; acc[1][1] += a.y*w.y; acc[1][2] += a.y*w.z; acc[1][3] += a.y*w.w;
      acc[2][0] += a.z*w.x; acc[2][1] += a.z*w.y; acc[2][2] += a.z*w.z; acc[2][3] += a.z*w.w;
      acc[3][0] += a.w*w.x; acc[3][1] += a.w*w.y; acc[3][2] += a.w*w.z; acc[3][3] += a.w*w.w;
    }
    __syncthreads();
  }
  #pragma unroll
  for (int i=0;i<4;i++){
    int row = m0 + ty*4 + i;
    #pragma unroll
    for (int j=0;j<4;j++){
      int col = n0 + tx*4 + j;
      if (col < N) {
        float vv = acc[i][j];
        if (bias) vv += bias[col];
        if (ACT == 1) vv = (vv > 20.f) ? vv : log1pf(expf(vv));            // softplus
        if (res) vv += res[(size_t)row*ldc + col];
        C[(size_t)row*ldc + col] = vv;
      }
    }
  }
}

// ============== MFMA GEMM on PRE-SPLIT bf16 hi/lo operands ==================
// 128x128 tile, BK=64, 4 waves (64x64 subtile = 4x4 frags of 16x16x32).
// 3 MFMA per fragment pair: ahi*bhi + ahi*blo + alo*bhi (rel err ~2^-16).
// Staging = pure 16B loads + swizzled ds_write_b128 (no conversion VALU).
// LDS XOR-swizzle (slot ^= row&7): measured 0 bank conflicts.
// REV: read A rows time-reversed per batch (row ^ 2047).
// OUT: 0 = fp32 C (+bias/res), 1 = split-K raw partials, 2 = gelu -> bf16 hi/lo
template<int ACT, int OUT, bool REV>
__global__ __launch_bounds__(256,2) void gemm_mfma(
    const ushort* __restrict__ Ah_g, const ushort* __restrict__ Al_g, int ldaA,
    const ushort* __restrict__ Wh_g, const ushort* __restrict__ Wl_g,
    const float* __restrict__ bias, float* __restrict__ C,
    ushort* __restrict__ Oh, ushort* __restrict__ Ol,
    int ldc, const float* __restrict__ res,
    int M, int N, int K, int Kc)
{
  __shared__ short8b Ah[1024], Al_[1024], Bh[1024], Bl[1024];  // 4 x 16 KB
  const int tid = threadIdx.x;
  const int m0 = blockIdx.y*128, n0 = blockIdx.x*128;
  const int lane = tid & 63, wv = tid >> 6;
  const int wr = (wv>>1)*64, wc = (wv&1)*64;       // wave's 64x64 subtile
  const int li = lane & 15, lg = lane >> 4;
  const int sr = tid >> 1, sh = tid & 1;           // staging: row 0..127, k-half
  const int kbeg = (OUT==1) ? blockIdx.z*Kc : 0;
  const int nkt = ((OUT==1) ? Kc : K) >> 6;
  int ar = m0 + sr;
  if constexpr (REV) ar ^= (SEQ_-1);               // per-batch time reversal
  const ushort* pAh = Ah_g + (size_t)ar*ldaA + kbeg + sh*32;
  const ushort* pAl = Al_g + (size_t)ar*ldaA + kbeg + sh*32;
  const ushort* pWh = Wh_g + (size_t)(n0+sr)*K + kbeg + sh*32;
  const ushort* pWl = Wl_g + (size_t)(n0+sr)*K + kbeg + sh*32;

  f32x4 acc[4][4];
  #pragma unroll
  for (int i=0;i<4;i++)
    #pragma unroll
    for (int j=0;j<4;j++) acc[i][j] = (f32x4){0.f,0.f,0.f,0.f};

  short8b ra_h[4], ra_l[4], rw_h[4], rw_l[4];
  #pragma unroll
  for (int p=0;p<4;p++){
    ra_h[p] = *(const short8b*)(pAh + p*8);
    ra_l[p] = *(const short8b*)(pAl + p*8);
    rw_h[p] = *(const short8b*)(pWh + p*8);
    rw_l[p] = *(const short8b*)(pWl + p*8);
  }

  for (int kt=0; kt<nkt; ++kt){
    __syncthreads();                 // all waves done reading LDS (prev tile)
    #pragma unroll
    for (int p=0;p<4;p++){
      int sl = sr*8 + ((sh*4+p) ^ (sr&7));
      Ah[sl]=ra_h[p]; Al_[sl]=ra_l[p]; Bh[sl]=rw_h[p]; Bl[sl]=rw_l[p];
    }
    __syncthreads();
    if (kt+1 < nkt){                 // prefetch next tile; drains under MFMA
      size_t off = (size_t)(kt+1)*64;
      #pragma unroll
      for (int p=0;p<4;p++){
        ra_h[p] = *(const short8b*)(pAh + off + p*8);
        ra_l[p] = *(const short8b*)(pAl + off + p*8);
        rw_h[p] = *(const short8b*)(pWh + off + p*8);
        rw_l[p] = *(const short8b*)(pWl + off + p*8);
      }
    }
    #pragma unroll
    for (int ks=0;ks<2;ks++){
      short8b afh[4],afl[4],bfh[4],bfl[4];
      #pragma unroll
      for (int f=0; f<4; f++){
        int sl = (ks*4+lg) ^ (li&7);
        afh[f]=Ah[(wr+f*16+li)*8+sl]; afl[f]=Al_[(wr+f*16+li)*8+sl];
        bfh[f]=Bh[(wc+f*16+li)*8+sl]; bfl[f]=Bl[(wc+f*16+li)*8+sl];
      }
      #pragma unroll
      for (int fr=0;fr<4;fr++)
        #pragma unroll
        for (int fc=0;fc<4;fc++){
          acc[fr][fc]=__builtin_amdgcn_mfma_f32_16x16x32_bf16(afh[fr],bfh[fc],acc[fr][fc],0,0,0);
          acc[fr][fc]=__builtin_amdgcn_mfma_f32_16x16x32_bf16(afh[fr],bfl[fc],acc[fr][fc],0,0,0);
          acc[fr][fc]=__builtin_amdgcn_mfma_f32_16x16x32_bf16(afl[fr],bfh[fc],acc[fr][fc],0,0,0);
        }
    }
  }

  // C/D layout (m89-verified): col = lane&15, row = (lane>>4)*4 + reg
  if constexpr (OUT==1){
    float* P = C + (size_t)blockIdx.z*((size_t)M*N);
    #pragma unroll
    for (int fr=0;fr<4;fr++)
      #pragma unroll
      for (int fc=0;fc<4;fc++){
        int col = n0 + wc + fc*16 + li;
        int row = m0 + wr + fr*16 + lg*4;
        #pragma unroll
        for (int rg=0;rg<4;rg++)
          P[(size_t)(row+rg)*N + col] = acc[fr][fc][rg];
      }
  } else if constexpr (OUT==2){
    #pragma unroll
    for (int fr=0;fr<4;fr++)
      #pragma unroll
      for (int fc=0;fc<4;fc++){
        int col = n0 + wc + fc*16 + li;
        int row = m0 + wr + fr*16 + lg*4;
        float bv = bias ? bias[col] : 0.f;
        #pragma unroll
        for (int rg=0;rg<4;rg++){
          float t = acc[fr][fc][rg] + bv;
          t = 0.5f*t*(1.f+erff(t*0.70710678118654752f));   // exact gelu
          ushort h, lo_;
          split1(t, h, lo_);
          Oh[(size_t)(row+rg)*ldc + col] = h;
          Ol[(size_t)(row+rg)*ldc + col] = lo_;
        }
      }
  } else {
    #pragma unroll
    for (int fr=0;fr<4;fr++)
      #pragma unroll
      for (int fc=0;fc<4;fc++){
        int col = n0 + wc + fc*16 + li;
        int row = m0 + wr + fr*16 + lg*4;
        float bv = bias ? bias[col] : 0.f;
        #pragma unroll
        for (int rg=0;rg<4;rg++){
          float t = acc[fr][fc][rg] + bv;
          if (res) t += res[(size_t)(row+rg)*ldc + col];
          C[(size_t)(row+rg)*ldc + col] = t;
        }
      }
  }
}

// ---------------- split-K reduce: C = sum_k P[k] (+bias) (+res) --------------
__global__ __launch_bounds__(256) void reduce_split(const float* __restrict__ P,
    const float* __restrict__ bias, const float* __restrict__ res,
    float* __restrict__ C, int N, size_t elems, int nsplit)
{
  size_t i = ((size_t)blockIdx.x*256 + threadIdx.x)*4;
  float4 s = *(const float4*)(P + i);
  for (int k=1;k<nsplit;k++){
    float4 p = *(const float4*)(P + (size_t)k*elems + i);
    s.x+=p.x; s.y+=p.y; s.z+=p.z; s.w+=p.w;
  }
  if (bias){
    int col = (int)(i % (size_t)N);
    const float4 b = *(const float4*)(bias + col);
    s.x+=b.x; s.y+=b.y; s.z+=b.z; s.w+=b.w;
  }
  if (res){
    const float4 r = *(const float4*)(res + i);
    s.x+=r.x; s.y+=r.y; s.z+=r.z; s.w+=r.w;
  }
  *(float4*)(C + i) = s;
}

// ---------------- depthwise causal conv(4) + SiLU ----------------
__global__ __launch_bounds__(256) void conv_silu_kernel(const float* __restrict__ xz,
    const float* __restrict__ cw, const float* __restrict__ cb, float* __restrict__ xh)
{
  int idx = blockIdx.x*256 + threadIdx.x;   // over MR*DH
  int d = idx % DH;
  int row = idx / DH;
  int l = row & (SEQ_-1);
  const float* base = xz + (size_t)row*(2*DH) + d;
  float acc = cb[d];
  #pragma unroll
  for (int j=0;j<4;j++){
    int ll = l - 3 + j;
    if (ll >= 0) acc += cw[d*4+j] * base[(ptrdiff_t)(j-3)*(2*DH)];
  }
  xh[(size_t)row*DH + d] = acc * sigmoidf_(acc);
}

// ================= chunked selective scan, d-coalesced =================
// Phase 1: local scan from h=0 over CL steps -> hend[unit*NS+n], dtsum.
__global__ __launch_bounds__(256) void scan_p1_kernel(
    const float* __restrict__ dt0, const float* __restrict__ xh0, const float* __restrict__ xd0,
    const float* __restrict__ Al0,
    const float* __restrict__ dt1, const float* __restrict__ xh1, const float* __restrict__ xd1,
    const float* __restrict__ Al1,
    float* __restrict__ hend, float* __restrict__ dtsum)
{
  int tid = threadIdx.x;
  int bid = blockIdx.x;
  int dblk = bid % NDBLK;
  int t   = bid / NDBLK;          // db*NCH + c
  int c   = t & (NCH-1);
  int db  = t >> 5;               // dir*2 + b
  int dir = db >> 1, bb = db & 1;
  int d = dblk*256 + tid;
  const float* dt = dir ? dt1 : dt0;
  const float* xh = dir ? xh1 : xh0;
  const float* xd = dir ? xd1 : xd0;
  const float* Al = dir ? Al1 : Al0;

  __shared__ float sB[CL][NS];    // 4 KB
  {
    const float* xdb = xd + ((size_t)bb*SEQ_ + (size_t)c*CL)*80 + RK;
    int row = tid >> 2, part = tid & 3;   // 256 float4 = CL*NS floats
    *(float4*)&sB[row][part*4] = *(const float4*)(xdb + (size_t)row*80 + part*4);
  }
  float An[NS];
  {
    const float4* ap = (const float4*)(Al + (size_t)d*NS);
    #pragma unroll
    for (int q=0;q<4;q++){
      float4 a = ap[q];
      An[4*q+0] = -__expf(a.x); An[4*q+1] = -__expf(a.y);
      An[4*q+2] = -__expf(a.z); An[4*q+3] = -__expf(a.w);
    }
  }
  __syncthreads();

  float h[NS];
  #pragma unroll
  for (int n=0;n<NS;n++) h[n] = 0.f;
  float dts = 0.f;
  size_t base = ((size_t)bb*SEQ_ + (size_t)c*CL)*DH + d;
  #pragma unroll 4
  for (int l=0;l<CL;++l){
    float dtv = dt[base], uv = xh[base];
    float du = dtv*uv;
    float Bv[NS];
    *(float4*)&Bv[0]  = *(const float4*)&sB[l][0];
    *(float4*)&Bv[4]  = *(const float4*)&sB[l][4];
    *(float4*)&Bv[8]  = *(const float4*)&sB[l][8];
    *(float4*)&Bv[12] = *(const float4*)&sB[l][12];
    #pragma unroll
    for (int n=0;n<NS;n++)
      h[n] = h[n]*__expf(dtv*An[n]) + du*Bv[n];
    dts += dtv;
    base += DH;
  }
  size_t unit = ((size_t)db*DH + d)*NCH + c;
  float4* hp = (float4*)(hend + unit*NS);
  hp[0] = make_float4(h[0],h[1],h[2],h[3]);
  hp[1] = make_float4(h[4],h[5],h[6],h[7]);
  hp[2] = make_float4(h[8],h[9],h[10],h[11]);
  hp[3] = make_float4(h[12],h[13],h[14],h[15]);
  dtsum[(size_t)c*NCHAN + (size_t)db*DH + d] = dts;   // [c][ch] layout: coalesced
}

// Phase 2: per (channel, n): sequential over NCH chunks; hend -> hstart prefix.
__global__ __launch_bounds__(256) void scan_p2_kernel(
    const float* __restrict__ Al0, const float* __restrict__ Al1,
    float* __restrict__ hend, const float* __restrict__ dtsum)
{
  int t = blockIdx.x*256 + threadIdx.x;      // 0 .. NCHAN*NS-1
  int n = t & 15;
  int ch = t >> 4;
  int d  = ch % DH;
  int dir = (ch / DH) >> 1;
  const float* Al = dir ? Al1 : Al0;
  float An = -__expf(Al[d*NS + n]);
  float h0 = 0.f;
  size_t ub = (size_t)ch * NCH;
  #pragma unroll
  for (int c = 0; c < NCH; ++c) {
    float P  = __expf(An * dtsum[(size_t)c*NCHAN + ch]);
    float he = hend[(ub + c)*NS + n];
    hend[(ub + c)*NS + n] = h0;              // now holds hstart for chunk c
    h0 = h0 * P + he;
  }
}

// Phase 3: recurrence from hstart; gated output -> bf16 hi/lo into the dead
// x-half of xz: per row (4*DH ushorts of x-slot) = [hi: d=0..DH) [lo: d=0..DH).
__global__ __launch_bounds__(256) void scan_p3_kernel(
    const float* __restrict__ dt0, const float* __restrict__ xh0, const float* __restrict__ xd0,
    const float* __restrict__ z0, const float* __restrict__ Al0, const float* __restrict__ Dp0,
    ushort* __restrict__ yg0,
    const float* __restrict__ dt1, const float* __restrict__ xh1, const float* __restrict__ xd1,
    const float* __restrict__ z1, const float* __restrict__ Al1, const float* __restrict__ Dp1,
    ushort* __restrict__ yg1,
    const float* __restrict__ hstart)
{
  int tid = threadIdx.x;
  int bid = blockIdx.x;
  int dblk = bid % NDBLK;
  int t   = bid / NDBLK;
  int c   = t & (NCH-1);
  int db  = t >> 5;
  int dir = db >> 1, bb = db & 1;
  int d = dblk*256 + tid;
  const float* dt = dir ? dt1 : dt0;
  const float* xh = dir ? xh1 : xh0;
  const float* xd = dir ? xd1 : xd0;
  const float* zp = dir ? z1  : z0;
  const float* Al = dir ? Al1 : Al0;
  const float* Dp = dir ? Dp1 : Dp0;
  ushort*      yg = dir ? yg1 : yg0;

  __shared__ float sBC[CL][2*NS];   // 8 KB
  {
    const float* xdb = xd + ((size_t)bb*SEQ_ + (size_t)c*CL)*80 + RK;
    #pragma unroll
    for (int i=0;i<2;i++){
      int idx = tid + i*256;        // 512 float4 = CL*2*NS floats
      int row = idx >> 3, part = idx & 7;
      *(float4*)&sBC[row][part*4] = *(const float4*)(xdb + (size_t)row*80 + part*4);
    }
  }
  float An[NS];
  {
    const float4* ap = (const float4*)(Al + (size_t)d*NS);
    #pragma unroll
    for (int q=0;q<4;q++){
      float4 a = ap[q];
      An[4*q+0] = -__expf(a.x); An[4*q+1] = -__expf(a.y);
      An[4*q+2] = -__expf(a.z); An[4*q+3] = -__expf(a.w);
    }
  }
  float Dd = Dp[d];
  __syncthreads();

  size_t unit = ((size_t)db*DH + d)*NCH + c;
  float h[NS];
  {
    const float4* hp = (const float4*)(hstart + unit*NS);
    float4 h0=hp[0], h1=hp[1], h2=hp[2], h3=hp[3];
    h[0]=h0.x; h[1]=h0.y; h[2]=h0.z; h[3]=h0.w;
    h[4]=h1.x; h[5]=h1.y; h[6]=h1.z; h[7]=h1.w;
    h[8]=h2.x; h[9]=h2.y; h[10]=h2.z; h[11]=h2.w;
    h[12]=h3.x; h[13]=h3.y; h[14]=h3.z; h[15]=h3.w;
  }
  size_t base = ((size_t)bb*SEQ_ + (size_t)c*CL)*DH + d;
  size_t zidx = ((size_t)bb*SEQ_ + (size_t)c*CL)*(size_t)(2*DH) + DH + d;
  size_t yrow = ((size_t)bb*SEQ_ + (size_t)c*CL)*(size_t)(4*DH) + d;
  #pragma unroll 2
  for (int l=0;l<CL;++l){
    float dtv = dt[base], uv = xh[base];
    float zv = zp[zidx];
    float du = dtv*uv;
    float Bv[NS], Cv[NS];
    *(float4*)&Bv[0]  = *(const float4*)&sBC[l][0];
    *(float4*)&Bv[4]  = *(const float4*)&sBC[l][4];
    *(float4*)&Bv[8]  = *(const float4*)&sBC[l][8];
    *(float4*)&Bv[12] = *(const float4*)&sBC[l][12];
    *(float4*)&Cv[0]  = *(const float4*)&sBC[l][16];
    *(float4*)&Cv[4]  = *(const float4*)&sBC[l][20];
    *(float4*)&Cv[8]  = *(const float4*)&sBC[l][24];
    *(float4*)&Cv[12] = *(const float4*)&sBC[l][28];
    float y = 0.f;
    #pragma unroll
    for (int n=0;n<NS;n++){
      h[n] = h[n]*__expf(dtv*An[n]) + du*Bv[n];
      y = fmaf(h[n], Cv[n], y);
    }
    float yv = (y + uv*Dd) * (zv * sigmoidf_(zv));
    ushort hh, ll;
    split1(yv, hh, ll);
    yg[yrow] = hh; yg[yrow + DH] = ll;
    base += DH; zidx += 2*DH; yrow += 4*DH;
  }
}

template<int ACT>
static inline void launch_gemm(const float* A, int lda, const float* W, const float* bias,
                               float* C, int ldc, const float* res,
                               int M, int N, int K, hipStream_t s)
{
  dim3 grid((N+63)/64, M/64);
  gemm_nt<ACT><<<grid, dim3(256), 0, s>>>(A, lda, W, bias, C, ldc, res, M, N, K);
}

extern "C" void kernel_launch(void* const* d_in, const int* in_sizes, int n_in,
                              void* d_out, int out_size, void* d_ws, size_t ws_size,
                              hipStream_t stream)
{
  const float* x        = (const float*)d_in[0];
  const float* f_in_w   = (const float*)d_in[1];
  const float* f_conv_w = (const float*)d_in[2];
  const float* f_conv_b = (const float*)d_in[3];
  const float* f_xproj  = (const float*)d_in[4];
  const float* f_dt_w   = (const float*)d_in[5];
  const float* f_dt_b   = (const float*)d_in[6];
  const float* f_A_log  = (const float*)d_in[7];
  const float* f_D      = (const float*)d_in[8];
  const float* f_out_w  = (const float*)d_in[9];
  const float* b_in_w   = (const float*)d_in[10];
  const float* b_conv_w = (const float*)d_in[11];
  const float* b_conv_b = (const float*)d_in[12];
  const float* b_xproj  = (const float*)d_in[13];
  const float* b_dt_w   = (const float*)d_in[14];
  const float* b_dt_b   = (const float*)d_in[15];
  const float* b_A_log  = (const float*)d_in[16];
  const float* b_D      = (const float*)d_in[17];
  const float* b_out_w  = (const float*)d_in[18];
  const float* ln1_g    = (const float*)d_in[19];
  const float* ln1_b    = (const float*)d_in[20];
  const float* ln2_g    = (const float*)d_in[21];
  const float* ln2_b    = (const float*)d_in[22];
  const float* ff_w1    = (const float*)d_in[23];
  const float* ff_b1    = (const float*)d_in[24];
  const float* ff_w2    = (const float*)d_in[25];
  const float* ff_b2    = (const float*)d_in[26];
  float* out = (float*)d_out;

  float* ws = (float*)d_ws;
  size_t o = 0;
  float* xz_f   = ws + o; o += (size_t)MR*2*DH;     // 12,582,912
  float* xz_b   = ws + o; o += (size_t)MR*2*DH;
  float* xh_f   = ws + o; o += (size_t)MR*DH;       // 6,291,456
  float* xh_b   = ws + o; o += (size_t)MR*DH;
  float* xdbl_f = ws + o; o += (size_t)MR*80;       // 327,680
  float* xdbl_b = ws + o; o += (size_t)MR*80;
  float* dtb_f  = ws + o; o += (size_t)MR*DH;
  float* dtb_b  = ws + o; o += (size_t)MR*DH;
  float* xnbf   = ws + o; o += (size_t)MR*DM;       // 2 ushort arrays MR*DM (hi,lo)
  float* dtsum  = ws + o; o += (size_t)NCHAN*NCH;   // 196,608
  float* wbf    = ws + o; o += (size_t)2*(2*DH*DM); // 4,718,592 fl = 9,437,184 ush
  // total: 59,047,936 floats = 236.2 MB

  // bf16 activation buffers
  ushort* xnh = (ushort*)xnbf;
  ushort* xnl = xnh + (size_t)MR*DM;
  // yg hi/lo live in the dead x-half of xz ([row][4*DH ushorts]: hi then lo)
  ushort* yg_f = (ushort*)xz_f;
  ushort* yg_b = (ushort*)xz_b;
  // weight region (time-shared: in_w -> out_w -> ff)
  ushort* wreg = (ushort*)wbf;
  ushort* f_inh = wreg;                       ushort* f_inl = wreg + (size_t)2*DH*DM;
  ushort* b_inh = wreg + (size_t)2*(2*DH*DM); ushort* b_inl = wreg + (size_t)3*(2*DH*DM);
  ushort* f_oth = wreg;                       ushort* f_otl = wreg + (size_t)DM*DH;
  ushort* b_oth = wreg + (size_t)2*DM*DH;     ushort* b_otl = wreg + (size_t)3*DM*DH;
  ushort* w1h   = wreg;                       ushort* w1l   = wreg + (size_t)4*DM*DM;
  ushort* w2h   = wreg + (size_t)2*(4*DM*DM); ushort* w2l   = wreg + (size_t)3*(4*DM*DM);
  // aliases (lifetime-safe reuse; stream is in-order)
  float* hend  = xnbf;                        // 3,145,728 fl == xnbf exactly (xn dead after in-proj)
  ushort* mh   = (ushort*)xh_f;               // ln2 out (xh dead after p3)
  ushort* ml   = mh + (size_t)MR*DM;
  float* fo    = xh_b;                        // out-proj results (xh_b dead after p3)
  float* bo    = xh_b + (size_t)MR*DM;
  float* part1 = dtb_f;                       // out-proj partials: 4*EL = dtb_f+dtb_b exactly
  ushort* ffhh = (ushort*)dtb_f;              // ff1 out bf16 (dtb dead after part1's last read)
  ushort* ffhl = ffhh + (size_t)MR*4*DM;
  float* part2 = xz_b;                        // ff_w2 partials (yg_b/z_b dead after out-proj)
  const size_t EL = (size_t)MR*DM;            // 3,145,728 (partial stride)

  // 0) in-proj weight splits (fp32 -> bf16 hi/lo)
  split_kernel<<<(2*DH*DM/4+255)/256, 256, 0, stream>>>(f_in_w, f_inh, f_inl, 2*DH*DM/4);
  split_kernel<<<(2*DH*DM/4+255)/256, 256, 0, stream>>>(b_in_w, b_inh, b_inl, 2*DH*DM/4);
  // 1) LN1 -> bf16 hi/lo
  ln1_kernel<<<MR, 256, 0, stream>>>(x, ln1_g, ln1_b, xnh, xnl);
  // 2) in-proj both dirs (M=4096, N=3072, K=768); b reads A rows reversed
  {
    dim3 grid((2*DH)/128, MR/128);
    gemm_mfma<0,0,false><<<grid, dim3(256), 0, stream>>>(xnh, xnl, DM, f_inh, f_inl,
        nullptr, xz_f, nullptr, nullptr, 2*DH, nullptr, MR, 2*DH, DM, 0);
    gemm_mfma<0,0,true><<<grid, dim3(256), 0, stream>>>(xnh, xnl, DM, b_inh, b_inl,
        nullptr, xz_b, nullptr, nullptr, 2*DH, nullptr, MR, 2*DH, DM, 0);
  }
  // 2b) out-proj weight splits (in_w region now dead)
  split_kernel<<<(DM*DH/4+255)/256, 256, 0, stream>>>(f_out_w, f_oth, f_otl, DM*DH/4);
  split_kernel<<<(DM*DH/4+255)/256, 256, 0, stream>>>(b_out_w, b_oth, b_otl, DM*DH/4);
  // 3) depthwise conv + SiLU
  conv_silu_kernel<<<(MR*DH)/256, 256, 0, stream>>>(xz_f, f_conv_w, f_conv_b, xh_f);
  conv_silu_kernel<<<(MR*DH)/256, 256, 0, stream>>>(xz_b, b_conv_w, b_conv_b, xh_b);
  // 4) x_dbl = xh @ xproj^T  (N=80) — skinny, fp32
  launch_gemm<0>(xh_f, DH, f_xproj, nullptr, xdbl_f, 80, nullptr, MR, 80, DH, stream);
  launch_gemm<0>(xh_b, DH, b_xproj, nullptr, xdbl_b, 80, nullptr, MR, 80, DH, stream);
  // 5) dt = softplus(dt_in @ dt_w^T + dt_b)   (K=48) — skinny, fp32
  launch_gemm<1>(xdbl_f, 80, f_dt_w, f_dt_b, dtb_f, DH, nullptr, MR, DH, RK, stream);
  launch_gemm<1>(xdbl_b, 80, b_dt_w, b_dt_b, dtb_b, DH, nullptr, MR, DH, RK, stream);
  // 6) chunked selective scan; gated output -> bf16 hi/lo into xz x-half
  scan_p1_kernel<<<4*NCH*NDBLK, 256, 0, stream>>>(
      dtb_f, xh_f, xdbl_f, f_A_log,
      dtb_b, xh_b, xdbl_b, b_A_log,
      hend, dtsum);
  scan_p2_kernel<<<(NCHAN*NS)/256, 256, 0, stream>>>(f_A_log, b_A_log, hend, dtsum);
  scan_p3_kernel<<<4*NCH*NDBLK, 256, 0, stream>>>(
      dtb_f, xh_f, xdbl_f, xz_f, f_A_log, f_D, yg_f,
      dtb_b, xh_b, xdbl_b, xz_b, b_A_log, b_D, yg_b,
      hend);
  // 7) out-proj per direction (N=768, K=1536): MFMA split-K x4 + reduce
  {
    dim3 grid(DM/128, MR/128, 4);
    gemm_mfma<0,1,false><<<grid, dim3(256), 0, stream>>>(yg_f, yg_f + DH, 4*DH,
        f_oth, f_otl, nullptr, part1, nullptr, nullptr, DM, nullptr, MR, DM, DH, DH/4);
    reduce_split<<<(int)(EL/1024), 256, 0, stream>>>(part1, nullptr, nullptr, fo, DM, EL, 4);
    gemm_mfma<0,1,false><<<grid, dim3(256), 0, stream>>>(yg_b, yg_b + DH, 4*DH,
        b_oth, b_otl, nullptr, part1, nullptr, nullptr, DM, nullptr, MR, DM, DH, DH/4);
    reduce_split<<<(int)(EL/1024), 256, 0, stream>>>(part1, nullptr, nullptr, bo, DM, EL, 4);
  }
  // 7b) FFN weight splits (out_w region now dead)
  split_kernel<<<(4*DM*DM/4+255)/256, 256, 0, stream>>>(ff_w1, w1h, w1l, 4*DM*DM/4);
  split_kernel<<<(4*DM*DM/4+255)/256, 256, 0, stream>>>(ff_w2, w2h, w2l, 4*DM*DM/4);
  // 8) LN2 of fo + reverse(bo) -> bf16 hi/lo
  ln2_kernel<<<MR, 256, 0, stream>>>(fo, bo, ln2_g, ln2_b, mh, ml);
  // 9) FFN: w1 (N=3072,K=768) + gelu -> bf16 hi/lo; w2 (N=768,K=3072) split-K x4
  {
    dim3 grid1((4*DM)/128, MR/128);
    gemm_mfma<2,2,false><<<grid1, dim3(256), 0, stream>>>(mh, ml, DM, w1h, w1l,
        ff_b1, nullptr, ffhh, ffhl, 4*DM, nullptr, MR, 4*DM, DM, 0);
    dim3 grid2(DM/128, MR/128, 4);
    gemm_mfma<0,1,false><<<grid2, dim3(256), 0, stream>>>(ffhh, ffhl, 4*DM, w2h, w2l,
        nullptr, part2, nullptr, nullptr, DM, nullptr, MR, DM, 4*DM, (4*DM)/4);
    reduce_split<<<(int)(EL/1024), 256, 0, stream>>>(part2, ff_b2, x, out, DM, EL, 4);
  }
}

// Round 6
// 905.446 us; speedup vs baseline: 2.7154x; 1.0669x over previous
//
#include <hip/hip_runtime.h>
#include <cstdint>
#include <cstddef>

#define BATCH_ 2
#define SEQ_ 2048
#define DM 768      // d_model
#define DH 1536     // d_inner
#define NS 16      // d_state
#define RK 48       // dt_rank
#define MR (BATCH_*SEQ_)   // 4096 rows
#define NCH 32      // scan chunks
#define CL (SEQ_/NCH)      // 64 steps per chunk
#define NCHAN (2*BATCH_*DH)        // 6144 (dir,b,d) channels
#define NDBLK (DH/256)             // 6 d-blocks per (dir,b,chunk)

typedef __attribute__((ext_vector_type(8))) short short8b;   // 8 bf16 = 4 VGPR
typedef __attribute__((ext_vector_type(4))) float f32x4;
typedef __attribute__((address_space(1))) const unsigned int gas_u32;
typedef __attribute__((address_space(3))) unsigned int las_u32;

__device__ __forceinline__ float sigmoidf_(float x){ return 1.f/(1.f+__expf(-x)); }

// fp32 -> bf16 hi (truncate) + bf16 lo (residual, truncate). rel err ~2^-16.
__device__ __forceinline__ void split1(float x, ushort& h, ushort& l){
  unsigned u = __float_as_uint(x);
  h = (ushort)(u >> 16);
  float lf = x - __uint_as_float(u & 0xFFFF0000u);   // exact
  l = (ushort)(__float_as_uint(lf) >> 16);
}

// ---------------- one-time weight split: fp32 -> bf16 hi/lo ------------------
__global__ __launch_bounds__(256) void split_kernel(const float* __restrict__ in,
    ushort* __restrict__ hi, ushort* __restrict__ lo, int n4)
{
  int i = blockIdx.x*256 + threadIdx.x;
  if (i >= n4) return;
  float4 v = ((const float4*)in)[i];
  ushort h0,h1,h2,h3,l0,l1,l2,l3;
  split1(v.x,h0,l0); split1(v.y,h1,l1); split1(v.z,h2,l2); split1(v.w,h3,l3);
  ((ushort4*)hi)[i] = make_ushort4(h0,h1,h2,h3);
  ((ushort4*)lo)[i] = make_ushort4(l0,l1,l2,l3);
}

// ------------- LayerNorm 1 -> bf16 hi/lo xn ---------------------------------
__global__ __launch_bounds__(256) void ln1_kernel(const float* __restrict__ x,
    const float* __restrict__ g, const float* __restrict__ bta,
    ushort* __restrict__ xnh, ushort* __restrict__ xnl)
{
  int row = blockIdx.x;            // b*SEQ + l
  int tid = threadIdx.x;
  __shared__ float s1[256], s2[256];
  float v[3]; float sum=0.f, sq=0.f;
  const float* xr = x + (size_t)row*DM;
  #pragma unroll
  for (int i=0;i<3;i++){ v[i] = xr[tid + i*256]; sum += v[i]; sq += v[i]*v[i]; }
  s1[tid]=sum; s2[tid]=sq; __syncthreads();
  for (int off=128; off>0; off>>=1){
    if (tid<off){ s1[tid]+=s1[tid+off]; s2[tid]+=s2[tid+off]; }
    __syncthreads();
  }
  float mean = s1[0] * (1.f/DM);
  float var  = s2[0] * (1.f/DM) - mean*mean;
  float rstd = rsqrtf(var + 1e-5f);
  #pragma unroll
  for (int i=0;i<3;i++){
    int c = tid + i*256;
    float val = (v[i]-mean)*rstd*g[c] + bta[c];
    ushort h, lo_;
    split1(val, h, lo_);
    xnh[(size_t)row*DM + c] = h;  xnl[(size_t)row*DM + c] = lo_;
  }
}

// ------------- LayerNorm 2: m = LN(fo + reverse(bo)) -> bf16 hi/lo ----------
__global__ __launch_bounds__(256) void ln2_kernel(const float* __restrict__ fo,
    const float* __restrict__ bo, const float* __restrict__ g,
    const float* __restrict__ bta, ushort* __restrict__ mh, ushort* __restrict__ ml)
{
  int row = blockIdx.x;
  int tid = threadIdx.x;
  int bb = row >> 11, l = row & (SEQ_-1);
  __shared__ float s1[256], s2[256];
  size_t rrow = ((size_t)bb*SEQ_ + (SEQ_-1-l))*DM;
  float v[3]; float sum=0.f, sq=0.f;
  #pragma unroll
  for (int i=0;i<3;i++){
    int c = tid + i*256;
    v[i] = fo[(size_t)row*DM + c] + bo[rrow + c];
    sum += v[i]; sq += v[i]*v[i];
  }
  s1[tid]=sum; s2[tid]=sq; __syncthreads();
  for (int off=128; off>0; off>>=1){
    if (tid<off){ s1[tid]+=s1[tid+off]; s2[tid]+=s2[tid+off]; }
    __syncthreads();
  }
  float mean = s1[0] * (1.f/DM);
  float var  = s2[0] * (1.f/DM) - mean*mean;
  float rstd = rsqrtf(var + 1e-5f);
  #pragma unroll
  for (int i=0;i<3;i++){
    int c = tid + i*256;
    float val = (v[i]-mean)*rstd*g[c] + bta[c];
    ushort h, lo_;
    split1(val, h, lo_);
    mh[(size_t)row*DM + c] = h;  ml[(size_t)row*DM + c] = lo_;
  }
}

// ---------------- small tiled GEMM (skinny N or K), fp32 --------------------
// ACT: 0=none, 1=softplus
template<int ACT>
__global__ __launch_bounds__(256) void gemm_nt(const float* __restrict__ A, int lda,
    const float* __restrict__ W, const float* __restrict__ bias,
    float* __restrict__ C, int ldc, const float* __restrict__ res,
    int M, int N, int K)
{
  __shared__ float As[16][64];
  __shared__ float Ws[16][64];
  int tid = threadIdx.x;
  int tx = tid & 15, ty = tid >> 4;
  int m0 = blockIdx.y * 64, n0 = blockIdx.x * 64;
  int lm = tid >> 2;          // 0..63
  int lk = (tid & 3) * 4;     // 0,4,8,12
  float acc[4][4] = {};
  for (int k0 = 0; k0 < K; k0 += 16) {
    float4 av = *(const float4*)(A + (size_t)(m0+lm)*lda + k0 + lk);
    As[lk+0][lm] = av.x; As[lk+1][lm] = av.y; As[lk+2][lm] = av.z; As[lk+3][lm] = av.w;
    int wn = n0 + lm;
    float4 wv = make_float4(0.f,0.f,0.f,0.f);
    if (wn < N) wv = *(const float4*)(W + (size_t)wn*K + k0 + lk);
    Ws[lk+0][lm] = wv.x; Ws[lk+1][lm] = wv.y; Ws[lk+2][lm] = wv.z; Ws[lk+3][lm] = wv.w;
    __syncthreads();
    #pragma unroll
    for (int k = 0; k < 16; ++k) {
      float4 a = *(const float4*)&As[k][ty*4];
      float4 w = *(const float4*)&Ws[k][tx*4];
      acc[0][0] += a.x*w.x; acc[0][1] += a.x*w.y; acc[0][2] += a.x*w.z; acc[0][3] += a.x*w.w;
      acc[1][0] += a.y*w.x; acc[1][1] += a.y*w.y; acc[1][2] += a.y*w.z; acc[1][3] += a.y*w.w;
      acc[2][0] += a.z*w.x; acc[2][1] += a.z*w.y; acc[2][2] += a.z*w.z; acc[2][3] += a.z*w.w;
      acc[3][0] += a.w*w.x; acc[3][1] += a.w*w.y; acc[3][2] += a.w*w.z; acc[3][3] += a.w*w.w;
    }
    __syncthreads();
  }
  #pragma unroll
  for (int i=0;i<4;i++){
    int row = m0 + ty*4 + i;
    #pragma unroll
    for (int j=0;j<4;j++){
      int col = n0 + tx*4 + j;
      if (col < N) {
        float vv = acc[i][j];
        if (bias) vv += bias[col];
        if (ACT == 1) vv = (vv > 20.f) ? vv : log1pf(expf(vv));            // softplus
        if (res) vv += res[(size_t)row*ldc + col];
        C[(size_t)row*ldc + col] = vv;
      }
    }
  }
}

// ============== MFMA GEMM, m97-structure: global_load_lds staging ===========
// 128x128 tile, BK=32, 4 waves (64x64 subtile = 4x4 frags of 16x16x32).
// 3 MFMA per fragment pair: ahi*bhi + ahi*blo + alo*bhi (rel err ~2^-16).
// LDS 32 KB: A rows [0,1024), B rows [1024,2048); each row = 128 B = 8 slots
// of 16 B; logical slots 0-3 = hi k-chunks, 4-7 = lo k-chunks; physical slot
// = logical ^ (row&7). Staged via global_load_lds(16B): linear LDS dest +
// pre-swizzled per-lane global source (rule 21: source perm == read perm).
// Reads: every 8 consecutive lanes cover all 8 slots -> conflict-free.
// REV: read A rows time-reversed per batch (row ^ 2047).
// OUT: 0 = fp32 C (+bias/res), 1 = split-K raw partials, 2 = gelu -> bf16 hi/lo
template<int ACT, int OUT, bool REV>
__global__ __launch_bounds__(256,3) void gemm_mfma(
    const ushort* __restrict__ Ah_g, const ushort* __restrict__ Al_g, int ldaA,
    const ushort* __restrict__ Wh_g, const ushort* __restrict__ Wl_g,
    const float* __restrict__ bias, float* __restrict__ C,
    ushort* __restrict__ Oh, ushort* __restrict__ Ol,
    int ldc, const float* __restrict__ res,
    int M, int N, int K, int Kc)
{
  __shared__ short8b L[2048];          // 32 KB
  const int tid = threadIdx.x;
  const int m0 = blockIdx.y*128, n0 = blockIdx.x*128;
  const int lane = tid & 63, wv = tid >> 6;
  const int wr = (wv>>1)*64, wc = (wv&1)*64;       // wave's 64x64 subtile
  const int li = lane & 15, lg = lane >> 4;
  const int kbeg = (OUT==1) ? blockIdx.z*Kc : 0;
  const int nkt = ((OUT==1) ? Kc : K) >> 5;

  // staging: lane l fills LDS row (base + (l>>3)), phys slot (l&7), which must
  // hold logical slot sl = (l&7) ^ (l>>3): hi chunk sl (<4) or lo chunk sl-4.
  const int lr8 = lane >> 3, ls = lane & 7;
  const int sl = ls ^ lr8;
  const int chunk = (sl & 3) * 8;                  // k-elem offset of 16B piece
  const ushort* gA = (sl < 4) ? Ah_g : Al_g;
  const ushort* gB = (sl < 4) ? Wh_g : Wl_g;
  const ushort* aAddr[4]; const ushort* bAddr[4];
  #pragma unroll
  for (int i=0;i<4;i++){
    int rg = m0 + wv*32 + i*8 + lr8;
    if constexpr (REV) rg ^= (SEQ_-1);             // per-batch time reversal
    aAddr[i] = gA + (size_t)rg*ldaA + kbeg + chunk;
    int rb = n0 + wv*32 + i*8 + lr8;
    bAddr[i] = gB + (size_t)rb*K + kbeg + chunk;
  }

  f32x4 acc[4][4];
  #pragma unroll
  for (int i=0;i<4;i++)
    #pragma unroll
    for (int j=0;j<4;j++) acc[i][j] = (f32x4){0.f,0.f,0.f,0.f};

  for (int kt=0; kt<nkt; ++kt){
    const int ko = kt*32;                          // k-elems this tile
    #pragma unroll
    for (int i=0;i<4;i++){
      __builtin_amdgcn_global_load_lds((gas_u32*)(aAddr[i]+ko),
          (las_u32*)&L[(wv*32+i*8)*8], 16, 0, 0);
      __builtin_amdgcn_global_load_lds((gas_u32*)(bAddr[i]+ko),
          (las_u32*)&L[1024+(wv*32+i*8)*8], 16, 0, 0);
    }
    __syncthreads();                               // vmcnt drain + barrier
    short8b afh[4],afl[4],bfh[4],bfl[4];
    #pragma unroll
    for (int f=0; f<4; f++){
      int sa = (wr+f*16+li)*8 + (lg ^ (li&7));
      int sb = 1024 + (wc+f*16+li)*8 + (lg ^ (li&7));
      afh[f]=L[sa]; afl[f]=L[sa^4];
      bfh[f]=L[sb]; bfl[f]=L[sb^4];
    }
    #pragma unroll
    for (int fr=0;fr<4;fr++)
      #pragma unroll
      for (int fc=0;fc<4;fc++){
        acc[fr][fc]=__builtin_amdgcn_mfma_f32_16x16x32_bf16(afh[fr],bfh[fc],acc[fr][fc],0,0,0);
        acc[fr][fc]=__builtin_amdgcn_mfma_f32_16x16x32_bf16(afh[fr],bfl[fc],acc[fr][fc],0,0,0);
        acc[fr][fc]=__builtin_amdgcn_mfma_f32_16x16x32_bf16(afl[fr],bfh[fc],acc[fr][fc],0,0,0);
      }
    __syncthreads();                               // LDS consumed before restage
  }

  // C/D layout (m89-verified): col = lane&15, row = (lane>>4)*4 + reg
  if constexpr (OUT==1){
    float* P = C + (size_t)blockIdx.z*((size_t)M*N);
    #pragma unroll
    for (int fr=0;fr<4;fr++)
      #pragma unroll
      for (int fc=0;fc<4;fc++){
        int col = n0 + wc + fc*16 + li;
        int row = m0 + wr + fr*16 + lg*4;
        #pragma unroll
        for (int rg=0;rg<4;rg++)
          P[(size_t)(row+rg)*N + col] = acc[fr][fc][rg];
      }
  } else if constexpr (OUT==2){
    #pragma unroll
    for (int fr=0;fr<4;fr++)
      #pragma unroll
      for (int fc=0;fc<4;fc++){
        int col = n0 + wc + fc*16 + li;
        int row = m0 + wr + fr*16 + lg*4;
        float bv = bias ? bias[col] : 0.f;
        #pragma unroll
        for (int rg=0;rg<4;rg++){
          float t = acc[fr][fc][rg] + bv;
          t = 0.5f*t*(1.f+erff(t*0.70710678118654752f));   // exact gelu
          ushort h, lo_;
          split1(t, h, lo_);
          Oh[(size_t)(row+rg)*ldc + col] = h;
          Ol[(size_t)(row+rg)*ldc + col] = lo_;
        }
      }
  } else {
    #pragma unroll
    for (int fr=0;fr<4;fr++)
      #pragma unroll
      for (int fc=0;fc<4;fc++){
        int col = n0 + wc + fc*16 + li;
        int row = m0 + wr + fr*16 + lg*4;
        float bv = bias ? bias[col] : 0.f;
        #pragma unroll
        for (int rg=0;rg<4;rg++){
          float t = acc[fr][fc][rg] + bv;
          if (res) t += res[(size_t)(row+rg)*ldc + col];
          C[(size_t)(row+rg)*ldc + col] = t;
        }
      }
  }
}

// ---------------- split-K reduce: C = sum_k P[k] (+bias) (+res) --------------
__global__ __launch_bounds__(256) void reduce_split(const float* __restrict__ P,
    const float* __restrict__ bias, const float* __restrict__ res,
    float* __restrict__ C, int N, size_t elems, int nsplit)
{
  size_t i = ((size_t)blockIdx.x*256 + threadIdx.x)*4;
  float4 s = *(const float4*)(P + i);
  for (int k=1;k<nsplit;k++){
    float4 p = *(const float4*)(P + (size_t)k*elems + i);
    s.x+=p.x; s.y+=p.y; s.z+=p.z; s.w+=p.w;
  }
  if (bias){
    int col = (int)(i % (size_t)N);
    const float4 b = *(const float4*)(bias + col);
    s.x+=b.x; s.y+=b.y; s.z+=b.z; s.w+=b.w;
  }
  if (res){
    const float4 r = *(const float4*)(res + i);
    s.x+=r.x; s.y+=r.y; s.z+=r.z; s.w+=r.w;
  }
  *(float4*)(C + i) = s;
}

// ---------------- depthwise causal conv(4) + SiLU ----------------
__global__ __launch_bounds__(256) void conv_silu_kernel(const float* __restrict__ xz,
    const float* __restrict__ cw, const float* __restrict__ cb, float* __restrict__ xh)
{
  int idx = blockIdx.x*256 + threadIdx.x;   // over MR*DH
  int d = idx % DH;
  int row = idx / DH;
  int l = row & (SEQ_-1);
  const float* base = xz + (size_t)row*(2*DH) + d;
  float acc = cb[d];
  #pragma unroll
  for (int j=0;j<4;j++){
    int ll = l - 3 + j;
    if (ll >= 0) acc += cw[d*4+j] * base[(ptrdiff_t)(j-3)*(2*DH)];
  }
  xh[(size_t)row*DH + d] = acc * sigmoidf_(acc);
}

// ================= chunked selective scan, d-coalesced =================
// Phase 1: local scan from h=0 over CL steps -> hend[unit*NS+n], dtsum.
__global__ __launch_bounds__(256) void scan_p1_kernel(
    const float* __restrict__ dt0, const float* __restrict__ xh0, const float* __restrict__ xd0,
    const float* __restrict__ Al0,
    const float* __restrict__ dt1, const float* __restrict__ xh1, const float* __restrict__ xd1,
    const float* __restrict__ Al1,
    float* __restrict__ hend, float* __restrict__ dtsum)
{
  int tid = threadIdx.x;
  int bid = blockIdx.x;
  int dblk = bid % NDBLK;
  int t   = bid / NDBLK;          // db*NCH + c
  int c   = t & (NCH-1);
  int db  = t >> 5;               // dir*2 + b
  int dir = db >> 1, bb = db & 1;
  int d = dblk*256 + tid;
  const float* dt = dir ? dt1 : dt0;
  const float* xh = dir ? xh1 : xh0;
  const float* xd = dir ? xd1 : xd0;
  const float* Al = dir ? Al1 : Al0;

  __shared__ float sB[CL][NS];    // 4 KB
  {
    const float* xdb = xd + ((size_t)bb*SEQ_ + (size_t)c*CL)*80 + RK;
    int row = tid >> 2, part = tid & 3;   // 256 float4 = CL*NS floats
    *(float4*)&sB[row][part*4] = *(const float4*)(xdb + (size_t)row*80 + part*4);
  }
  float An[NS];
  {
    const float4* ap = (const float4*)(Al + (size_t)d*NS);
    #pragma unroll
    for (int q=0;q<4;q++){
      float4 a = ap[q];
      An[4*q+0] = -__expf(a.x); An[4*q+1] = -__expf(a.y);
      An[4*q+2] = -__expf(a.z); An[4*q+3] = -__expf(a.w);
    }
  }
  __syncthreads();

  float h[NS];
  #pragma unroll
  for (int n=0;n<NS;n++) h[n] = 0.f;
  float dts = 0.f;
  size_t base = ((size_t)bb*SEQ_ + (size_t)c*CL)*DH + d;
  #pragma unroll 4
  for (int l=0;l<CL;++l){
    float dtv = dt[base], uv = xh[base];
    float du = dtv*uv;
    float Bv[NS];
    *(float4*)&Bv[0]  = *(const float4*)&sB[l][0];
    *(float4*)&Bv[4]  = *(const float4*)&sB[l][4];
    *(float4*)&Bv[8]  = *(const float4*)&sB[l][8];
    *(float4*)&Bv[12] = *(const float4*)&sB[l][12];
    #pragma unroll
    for (int n=0;n<NS;n++)
      h[n] = h[n]*__expf(dtv*An[n]) + du*Bv[n];
    dts += dtv;
    base += DH;
  }
  size_t unit = ((size_t)db*DH + d)*NCH + c;
  float4* hp = (float4*)(hend + unit*NS);
  hp[0] = make_float4(h[0],h[1],h[2],h[3]);
  hp[1] = make_float4(h[4],h[5],h[6],h[7]);
  hp[2] = make_float4(h[8],h[9],h[10],h[11]);
  hp[3] = make_float4(h[12],h[13],h[14],h[15]);
  dtsum[(size_t)c*NCHAN + (size_t)db*DH + d] = dts;   // [c][ch] layout: coalesced
}

// Phase 2: per (channel, n): sequential over NCH chunks; hend -> hstart prefix.
__global__ __launch_bounds__(256) void scan_p2_kernel(
    const float* __restrict__ Al0, const float* __restrict__ Al1,
    float* __restrict__ hend, const float* __restrict__ dtsum)
{
  int t = blockIdx.x*256 + threadIdx.x;      // 0 .. NCHAN*NS-1
  int n = t & 15;
  int ch = t >> 4;
  int d  = ch % DH;
  int dir = (ch / DH) >> 1;
  const float* Al = dir ? Al1 : Al0;
  float An = -__expf(Al[d*NS + n]);
  float h0 = 0.f;
  size_t ub = (size_t)ch * NCH;
  #pragma unroll
  for (int c = 0; c < NCH; ++c) {
    float P  = __expf(An * dtsum[(size_t)c*NCHAN + ch]);
    float he = hend[(ub + c)*NS + n];
    hend[(ub + c)*NS + n] = h0;              // now holds hstart for chunk c
    h0 = h0 * P + he;
  }
}

// Phase 3: recurrence from hstart; gated output -> bf16 hi/lo into the dead
// x-half of xz: per row (4*DH ushorts of x-slot) = [hi: d=0..DH) [lo: d=0..DH).
__global__ __launch_bounds__(256) void scan_p3_kernel(
    const float* __restrict__ dt0, const float* __restrict__ xh0, const float* __restrict__ xd0,
    const float* __restrict__ z0, const float* __restrict__ Al0, const float* __restrict__ Dp0,
    ushort* __restrict__ yg0,
    const float* __restrict__ dt1, const float* __restrict__ xh1, const float* __restrict__ xd1,
    const float* __restrict__ z1, const float* __restrict__ Al1, const float* __restrict__ Dp1,
    ushort* __restrict__ yg1,
    const float* __restrict__ hstart)
{
  int tid = threadIdx.x;
  int bid = blockIdx.x;
  int dblk = bid % NDBLK;
  int t   = bid / NDBLK;
  int c   = t & (NCH-1);
  int db  = t >> 5;
  int dir = db >> 1, bb = db & 1;
  int d = dblk*256 + tid;
  const float* dt = dir ? dt1 : dt0;
  const float* xh = dir ? xh1 : xh0;
  const float* xd = dir ? xd1 : xd0;
  const float* zp = dir ? z1  : z0;
  const float* Al = dir ? Al1 : Al0;
  const float* Dp = dir ? Dp1 : Dp0;
  ushort*      yg = dir ? yg1 : yg0;

  __shared__ float sBC[CL][2*NS];   // 8 KB
  {
    const float* xdb = xd + ((size_t)bb*SEQ_ + (size_t)c*CL)*80 + RK;
    #pragma unroll
    for (int i=0;i<2;i++){
      int idx = tid + i*256;        // 512 float4 = CL*2*NS floats
      int row = idx >> 3, part = idx & 7;
      *(float4*)&sBC[row][part*4] = *(const float4*)(xdb + (size_t)row*80 + part*4);
    }
  }
  float An[NS];
  {
    const float4* ap = (const float4*)(Al + (size_t)d*NS);
    #pragma unroll
    for (int q=0;q<4;q++){
      float4 a = ap[q];
      An[4*q+0] = -__expf(a.x); An[4*q+1] = -__expf(a.y);
      An[4*q+2] = -__expf(a.z); An[4*q+3] = -__expf(a.w);
    }
  }
  float Dd = Dp[d];
  __syncthreads();

  size_t unit = ((size_t)db*DH + d)*NCH + c;
  float h[NS];
  {
    const float4* hp = (const float4*)(hstart + unit*NS);
    float4 h0=hp[0], h1=hp[1], h2=hp[2], h3=hp[3];
    h[0]=h0.x; h[1]=h0.y; h[2]=h0.z; h[3]=h0.w;
    h[4]=h1.x; h[5]=h1.y; h[6]=h1.z; h[7]=h1.w;
    h[8]=h2.x; h[9]=h2.y; h[10]=h2.z; h[11]=h2.w;
    h[12]=h3.x; h[13]=h3.y; h[14]=h3.z; h[15]=h3.w;
  }
  size_t base = ((size_t)bb*SEQ_ + (size_t)c*CL)*DH + d;
  size_t zidx = ((size_t)bb*SEQ_ + (size_t)c*CL)*(size_t)(2*DH) + DH + d;
  size_t yrow = ((size_t)bb*SEQ_ + (size_t)c*CL)*(size_t)(4*DH) + d;
  #pragma unroll 2
  for (int l=0;l<CL;++l){
    float dtv = dt[base], uv = xh[base];
    float zv = zp[zidx];
    float du = dtv*uv;
    float Bv[NS], Cv[NS];
    *(float4*)&Bv[0]  = *(const float4*)&sBC[l][0];
    *(float4*)&Bv[4]  = *(const float4*)&sBC[l][4];
    *(float4*)&Bv[8]  = *(const float4*)&sBC[l][8];
    *(float4*)&Bv[12] = *(const float4*)&sBC[l][12];
    *(float4*)&Cv[0]  = *(const float4*)&sBC[l][16];
    *(float4*)&Cv[4]  = *(const float4*)&sBC[l][20];
    *(float4*)&Cv[8]  = *(const float4*)&sBC[l][24];
    *(float4*)&Cv[12] = *(const float4*)&sBC[l][28];
    float y = 0.f;
    #pragma unroll
    for (int n=0;n<NS;n++){
      h[n] = h[n]*__expf(dtv*An[n]) + du*Bv[n];
      y = fmaf(h[n], Cv[n], y);
    }
    float yv = (y + uv*Dd) * (zv * sigmoidf_(zv));
    ushort hh, ll;
    split1(yv, hh, ll);
    yg[yrow] = hh; yg[yrow + DH] = ll;
    base += DH; zidx += 2*DH; yrow += 4*DH;
  }
}

template<int ACT>
static inline void launch_gemm(const float* A, int lda, const float* W, const float* bias,
                               float* C, int ldc, const float* res,
                               int M, int N, int K, hipStream_t s)
{
  dim3 grid((N+63)/64, M/64);
  gemm_nt<ACT><<<grid, dim3(256), 0, s>>>(A, lda, W, bias, C, ldc, res, M, N, K);
}

extern "C" void kernel_launch(void* const* d_in, const int* in_sizes, int n_in,
                              void* d_out, int out_size, void* d_ws, size_t ws_size,
                              hipStream_t stream)
{
  const float* x        = (const float*)d_in[0];
  const float* f_in_w   = (const float*)d_in[1];
  const float* f_conv_w = (const float*)d_in[2];
  const float* f_conv_b = (const float*)d_in[3];
  const float* f_xproj  = (const float*)d_in[4];
  const float* f_dt_w   = (const float*)d_in[5];
  const float* f_dt_b   = (const float*)d_in[6];
  const float* f_A_log  = (const float*)d_in[7];
  const float* f_D      = (const float*)d_in[8];
  const float* f_out_w  = (const float*)d_in[9];
  const float* b_in_w   = (const float*)d_in[10];
  const float* b_conv_w = (const float*)d_in[11];
  const float* b_conv_b = (const float*)d_in[12];
  const float* b_xproj  = (const float*)d_in[13];
  const float* b_dt_w   = (const float*)d_in[14];
  const float* b_dt_b   = (const float*)d_in[15];
  const float* b_A_log  = (const float*)d_in[16];
  const float* b_D      = (const float*)d_in[17];
  const float* b_out_w  = (const float*)d_in[18];
  const float* ln1_g    = (const float*)d_in[19];
  const float* ln1_b    = (const float*)d_in[20];
  const float* ln2_g    = (const float*)d_in[21];
  const float* ln2_b    = (const float*)d_in[22];
  const float* ff_w1    = (const float*)d_in[23];
  const float* ff_b1    = (const float*)d_in[24];
  const float* ff_w2    = (const float*)d_in[25];
  const float* ff_b2    = (const float*)d_in[26];
  float* out = (float*)d_out;

  float* ws = (float*)d_ws;
  size_t o = 0;
  float* xz_f   = ws + o; o += (size_t)MR*2*DH;     // 12,582,912
  float* xz_b   = ws + o; o += (size_t)MR*2*DH;
  float* xh_f   = ws + o; o += (size_t)MR*DH;       // 6,291,456
  float* xh_b   = ws + o; o += (size_t)MR*DH;
  float* xdbl_f = ws + o; o += (size_t)MR*80;       // 327,680
  float* xdbl_b = ws + o; o += (size_t)MR*80;
  float* dtb_f  = ws + o; o += (size_t)MR*DH;
  float* dtb_b  = ws + o; o += (size_t)MR*DH;
  float* xnbf   = ws + o; o += (size_t)MR*DM;       // 2 ushort arrays MR*DM (hi,lo)
  float* dtsum  = ws + o; o += (size_t)NCHAN*NCH;   // 196,608
  float* wbf    = ws + o; o += (size_t)2*(2*DH*DM); // 4,718,592 fl = 9,437,184 ush
  // total: 59,047,936 floats = 236.2 MB

  // bf16 activation buffers
  ushort* xnh = (ushort*)xnbf;
  ushort* xnl = xnh + (size_t)MR*DM;
  // yg hi/lo live in the dead x-half of xz ([row][4*DH ushorts]: hi then lo)
  ushort* yg_f = (ushort*)xz_f;
  ushort* yg_b = (ushort*)xz_b;
  // weight region (time-shared: in_w -> out_w -> ff)
  ushort* wreg = (ushort*)wbf;
  ushort* f_inh = wreg;                       ushort* f_inl = wreg + (size_t)2*DH*DM;
  ushort* b_inh = wreg + (size_t)2*(2*DH*DM); ushort* b_inl = wreg + (size_t)3*(2*DH*DM);
  ushort* f_oth = wreg;                       ushort* f_otl = wreg + (size_t)DM*DH;
  ushort* b_oth = wreg + (size_t)2*DM*DH;     ushort* b_otl = wreg + (size_t)3*DM*DH;
  ushort* w1h   = wreg;                       ushort* w1l   = wreg + (size_t)4*DM*DM;
  ushort* w2h   = wreg + (size_t)2*(4*DM*DM); ushort* w2l   = wreg + (size_t)3*(4*DM*DM);
  // aliases (lifetime-safe reuse; stream is in-order)
  float* hend  = xnbf;                        // 3,145,728 fl == xnbf exactly (xn dead after in-proj)
  ushort* mh   = (ushort*)xh_f;               // ln2 out (xh dead after p3)
  ushort* ml   = mh + (size_t)MR*DM;
  float* fo    = xh_b;                        // out-proj results (xh_b dead after p3)
  float* bo    = xh_b + (size_t)MR*DM;
  float* part1 = dtb_f;                       // out-proj partials: 4*EL = dtb_f+dtb_b exactly
  ushort* ffhh = (ushort*)dtb_f;              // ff1 out bf16 (dtb dead after part1's last read)
  ushort* ffhl = ffhh + (size_t)MR*4*DM;
  float* part2 = xz_b;                        // ff_w2 partials (yg_b/z_b dead after out-proj)
  const size_t EL = (size_t)MR*DM;            // 3,145,728 (partial stride)

  // 0) in-proj weight splits (fp32 -> bf16 hi/lo)
  split_kernel<<<(2*DH*DM/4+255)/256, 256, 0, stream>>>(f_in_w, f_inh, f_inl, 2*DH*DM/4);
  split_kernel<<<(2*DH*DM/4+255)/256, 256, 0, stream>>>(b_in_w, b_inh, b_inl, 2*DH*DM/4);
  // 1) LN1 -> bf16 hi/lo
  ln1_kernel<<<MR, 256, 0, stream>>>(x, ln1_g, ln1_b, xnh, xnl);
  // 2) in-proj both dirs (M=4096, N=3072, K=768); b reads A rows reversed
  {
    dim3 grid((2*DH)/128, MR/128);
    gemm_mfma<0,0,false><<<grid, dim3(256), 0, stream>>>(xnh, xnl, DM, f_inh, f_inl,
        nullptr, xz_f, nullptr, nullptr, 2*DH, nullptr, MR, 2*DH, DM, 0);
    gemm_mfma<0,0,true><<<grid, dim3(256), 0, stream>>>(xnh, xnl, DM, b_inh, b_inl,
        nullptr, xz_b, nullptr, nullptr, 2*DH, nullptr, MR, 2*DH, DM, 0);
  }
  // 2b) out-proj weight splits (in_w region now dead)
  split_kernel<<<(DM*DH/4+255)/256, 256, 0, stream>>>(f_out_w, f_oth, f_otl, DM*DH/4);
  split_kernel<<<(DM*DH/4+255)/256, 256, 0, stream>>>(b_out_w, b_oth, b_otl, DM*DH/4);
  // 3) depthwise conv + SiLU
  conv_silu_kernel<<<(MR*DH)/256, 256, 0, stream>>>(xz_f, f_conv_w, f_conv_b, xh_f);
  conv_silu_kernel<<<(MR*DH)/256, 256, 0, stream>>>(xz_b, b_conv_w, b_conv_b, xh_b);
  // 4) x_dbl = xh @ xproj^T  (N=80) — skinny, fp32
  launch_gemm<0>(xh_f, DH, f_xproj, nullptr, xdbl_f, 80, nullptr, MR, 80, DH, stream);
  launch_gemm<0>(xh_b, DH, b_xproj, nullptr, xdbl_b, 80, nullptr, MR, 80, DH, stream);
  // 5) dt = softplus(dt_in @ dt_w^T + dt_b)   (K=48) — skinny, fp32
  launch_gemm<1>(xdbl_f, 80, f_dt_w, f_dt_b, dtb_f, DH, nullptr, MR, DH, RK, stream);
  launch_gemm<1>(xdbl_b, 80, b_dt_w, b_dt_b, dtb_b, DH, nullptr, MR, DH, RK, stream);
  // 6) chunked selective scan; gated output -> bf16 hi/lo into xz x-half
  scan_p1_kernel<<<4*NCH*NDBLK, 256, 0, stream>>>(
      dtb_f, xh_f, xdbl_f, f_A_log,
      dtb_b, xh_b, xdbl_b, b_A_log,
      hend, dtsum);
  scan_p2_kernel<<<(NCHAN*NS)/256, 256, 0, stream>>>(f_A_log, b_A_log, hend, dtsum);
  scan_p3_kernel<<<4*NCH*NDBLK, 256, 0, stream>>>(
      dtb_f, xh_f, xdbl_f, xz_f, f_A_log, f_D, yg_f,
      dtb_b, xh_b, xdbl_b, xz_b, b_A_log, b_D, yg_b,
      hend);
  // 7) out-proj per direction (N=768, K=1536): MFMA split-K x4 + reduce
  {
    dim3 grid(DM/128, MR/128, 4);
    gemm_mfma<0,1,false><<<grid, dim3(256), 0, stream>>>(yg_f, yg_f + DH, 4*DH,
        f_oth, f_otl, nullptr, part1, nullptr, nullptr, DM, nullptr, MR, DM, DH, DH/4);
    reduce_split<<<(int)(EL/1024), 256, 0, stream>>>(part1, nullptr, nullptr, fo, DM, EL, 4);
    gemm_mfma<0,1,false><<<grid, dim3(256), 0, stream>>>(yg_b, yg_b + DH, 4*DH,
        b_oth, b_otl, nullptr, part1, nullptr, nullptr, DM, nullptr, MR, DM, DH, DH/4);
    reduce_split<<<(int)(EL/1024), 256, 0, stream>>>(part1, nullptr, nullptr, bo, DM, EL, 4);
  }
  // 7b) FFN weight splits (out_w region now dead)
  split_kernel<<<(4*DM*DM/4+255)/256, 256, 0, stream>>>(ff_w1, w1h, w1l, 4*DM*DM/4);
  split_kernel<<<(4*DM*DM/4+255)/256, 256, 0, stream>>>(ff_w2, w2h, w2l, 4*DM*DM/4);
  // 8) LN2 of fo + reverse(bo) -> bf16 hi/lo
  ln2_kernel<<<MR, 256, 0, stream>>>(fo, bo, ln2_g, ln2_b, mh, ml);
  // 9) FFN: w1 (N=3072,K=768) + gelu -> bf16 hi/lo; w2 (N=768,K=3072) split-K x4
  {
    dim3 grid1((4*DM)/128, MR/128);
    gemm_mfma<2,2,false><<<grid1, dim3(256), 0, stream>>>(mh, ml, DM, w1h, w1l,
        ff_b1, nullptr, ffhh, ffhl, 4*DM, nullptr, MR, 4*DM, DM, 0);
    dim3 grid2(DM/128, MR/128, 4);
    gemm_mfma<0,1,false><<<grid2, dim3(256), 0, stream>>>(ffhh, ffhl, 4*DM, w2h, w2l,
        nullptr, part2, nullptr, nullptr, DM, nullptr, MR, DM, 4*DM, (4*DM)/4);
    reduce_split<<<(int)(EL/1024), 256, 0, stream>>>(part2, ff_b2, x, out, DM, EL, 4);
  }
}

// Round 7
// 771.437 us; speedup vs baseline: 3.1871x; 1.1737x over previous
//
#include <hip/hip_runtime.h>
#include <cstdint>
#include <cstddef>

#define BATCH_ 2
#define SEQ_ 2048
#define DM 768      // d_model
#define DH 1536     // d_inner
#define NS 16      // d_state
#define RK 48       // dt_rank
#define MR (BATCH_*SEQ_)   // 4096 rows
#define NCH 32      // scan chunks
#define CL (SEQ_/NCH)      // 64 steps per chunk
#define NCHAN (2*BATCH_*DH)        // 6144 (dir,b,d) channels
#define NDBLK (DH/256)             // 6 d-blocks per (dir,b,chunk)

typedef __attribute__((ext_vector_type(8))) short short8b;   // 8 bf16 = 4 VGPR
typedef __attribute__((ext_vector_type(4))) float f32x4;
typedef __attribute__((address_space(1))) const unsigned int gas_u32;
typedef __attribute__((address_space(3))) unsigned int las_u32;

__device__ __forceinline__ float sigmoidf_(float x){ return 1.f/(1.f+__expf(-x)); }

// fp32 -> bf16 hi (truncate) + bf16 lo (residual, truncate). rel err ~2^-16.
__device__ __forceinline__ void split1(float x, ushort& h, ushort& l){
  unsigned u = __float_as_uint(x);
  h = (ushort)(u >> 16);
  float lf = x - __uint_as_float(u & 0xFFFF0000u);   // exact
  l = (ushort)(__float_as_uint(lf) >> 16);
}

// ---------------- one-time weight split: fp32 -> bf16 hi/lo ------------------
__global__ __launch_bounds__(256) void split_kernel(const float* __restrict__ in,
    ushort* __restrict__ hi, ushort* __restrict__ lo, int n4)
{
  int i = blockIdx.x*256 + threadIdx.x;
  if (i >= n4) return;
  float4 v = ((const float4*)in)[i];
  ushort h0,h1,h2,h3,l0,l1,l2,l3;
  split1(v.x,h0,l0); split1(v.y,h1,l1); split1(v.z,h2,l2); split1(v.w,h3,l3);
  ((ushort4*)hi)[i] = make_ushort4(h0,h1,h2,h3);
  ((ushort4*)lo)[i] = make_ushort4(l0,l1,l2,l3);
}

// ------------- LayerNorm 1 -> bf16 hi/lo xn ---------------------------------
__global__ __launch_bounds__(256) void ln1_kernel(const float* __restrict__ x,
    const float* __restrict__ g, const float* __restrict__ bta,
    ushort* __restrict__ xnh, ushort* __restrict__ xnl)
{
  int row = blockIdx.x;            // b*SEQ + l
  int tid = threadIdx.x;
  __shared__ float s1[256], s2[256];
  float v[3]; float sum=0.f, sq=0.f;
  const float* xr = x + (size_t)row*DM;
  #pragma unroll
  for (int i=0;i<3;i++){ v[i] = xr[tid + i*256]; sum += v[i]; sq += v[i]*v[i]; }
  s1[tid]=sum; s2[tid]=sq; __syncthreads();
  for (int off=128; off>0; off>>=1){
    if (tid<off){ s1[tid]+=s1[tid+off]; s2[tid]+=s2[tid+off]; }
    __syncthreads();
  }
  float mean = s1[0] * (1.f/DM);
  float var  = s2[0] * (1.f/DM) - mean*mean;
  float rstd = rsqrtf(var + 1e-5f);
  #pragma unroll
  for (int i=0;i<3;i++){
    int c = tid + i*256;
    float val = (v[i]-mean)*rstd*g[c] + bta[c];
    ushort h, lo_;
    split1(val, h, lo_);
    xnh[(size_t)row*DM + c] = h;  xnl[(size_t)row*DM + c] = lo_;
  }
}

// ------------- LayerNorm 2: m = LN(fo + reverse(bo)) -> bf16 hi/lo ----------
__global__ __launch_bounds__(256) void ln2_kernel(const float* __restrict__ fo,
    const float* __restrict__ bo, const float* __restrict__ g,
    const float* __restrict__ bta, ushort* __restrict__ mh, ushort* __restrict__ ml)
{
  int row = blockIdx.x;
  int tid = threadIdx.x;
  int bb = row >> 11, l = row & (SEQ_-1);
  __shared__ float s1[256], s2[256];
  size_t rrow = ((size_t)bb*SEQ_ + (SEQ_-1-l))*DM;
  float v[3]; float sum=0.f, sq=0.f;
  #pragma unroll
  for (int i=0;i<3;i++){
    int c = tid + i*256;
    v[i] = fo[(size_t)row*DM + c] + bo[rrow + c];
    sum += v[i]; sq += v[i]*v[i];
  }
  s1[tid]=sum; s2[tid]=sq; __syncthreads();
  for (int off=128; off>0; off>>=1){
    if (tid<off){ s1[tid]+=s1[tid+off]; s2[tid]+=s2[tid+off]; }
    __syncthreads();
  }
  float mean = s1[0] * (1.f/DM);
  float var  = s2[0] * (1.f/DM) - mean*mean;
  float rstd = rsqrtf(var + 1e-5f);
  #pragma unroll
  for (int i=0;i<3;i++){
    int c = tid + i*256;
    float val = (v[i]-mean)*rstd*g[c] + bta[c];
    ushort h, lo_;
    split1(val, h, lo_);
    mh[(size_t)row*DM + c] = h;  ml[(size_t)row*DM + c] = lo_;
  }
}

// ---------------- small tiled GEMM (skinny N or K), fp32 --------------------
// ACT: 0=none, 1=softplus. RAW=true: split-K partials -> C + z*M*N (no act).
template<int ACT, bool RAW>
__global__ __launch_bounds__(256) void gemm_nt(const float* __restrict__ A, int lda,
    const float* __restrict__ W, const float* __restrict__ bias,
    float* __restrict__ C, int ldc, const float* __restrict__ res,
    int M, int N, int K, int Kc)
{
  __shared__ float As[16][64];
  __shared__ float Ws[16][64];
  int tid = threadIdx.x;
  int tx = tid & 15, ty = tid >> 4;
  int m0 = blockIdx.y * 64, n0 = blockIdx.x * 64;
  int lm = tid >> 2;          // 0..63
  int lk = (tid & 3) * 4;     // 0,4,8,12
  const int kbeg = RAW ? blockIdx.z*Kc : 0;
  const int kend = RAW ? kbeg + Kc : K;
  float acc[4][4] = {};
  for (int k0 = kbeg; k0 < kend; k0 += 16) {
    float4 av = *(const float4*)(A + (size_t)(m0+lm)*lda + k0 + lk);
    As[lk+0][lm] = av.x; As[lk+1][lm] = av.y; As[lk+2][lm] = av.z; As[lk+3][lm] = av.w;
    int wn = n0 + lm;
    float4 wv = make_float4(0.f,0.f,0.f,0.f);
    if (wn < N) wv = *(const float4*)(W + (size_t)wn*K + k0 + lk);
    Ws[lk+0][lm] = wv.x; Ws[lk+1][lm] = wv.y; Ws[lk+2][lm] = wv.z; Ws[lk+3][lm] = wv.w;
    __syncthreads();
    #pragma unroll
    for (int k = 0; k < 16; ++k) {
      float4 a = *(const float4*)&As[k][ty*4];
      float4 w = *(const float4*)&Ws[k][tx*4];
      acc[0][0] += a.x*w.x; acc[0][1] += a.x*w.y; acc[0][2] += a.x*w.z; acc[0][3] += a.x*w.w;
      acc[1][0] += a.y*w.x; acc[1][1] += a.y*w.y; acc[1][2] += a.y*w.z; acc[1][3] += a.y*w.w;
      acc[2][0] += a.z*w.x; acc[2][1] += a.z*w.y; acc[2][2] += a.z*w.z; acc[2][3] += a.z*w.w;
      acc[3][0] += a.w*w.x; acc[3][1] += a.w*w.y; acc[3][2] += a.w*w.z; acc[3][3] += a.w*w.w;
    }
    __syncthreads();
  }
  if constexpr (RAW){
    float* P = C + (size_t)blockIdx.z*((size_t)M*N);
    #pragma unroll
    for (int i=0;i<4;i++){
      int row = m0 + ty*4 + i;
      #pragma unroll
      for (int j=0;j<4;j++){
        int col = n0 + tx*4 + j;
        if (col < N) P[(size_t)row*N + col] = acc[i][j];
      }
    }
  } else {
    #pragma unroll
    for (int i=0;i<4;i++){
      int row = m0 + ty*4 + i;
      #pragma unroll
      for (int j=0;j<4;j++){
        int col = n0 + tx*4 + j;
        if (col < N) {
          float vv = acc[i][j];
          if (bias) vv += bias[col];
          if (ACT == 1) vv = (vv > 20.f) ? vv : log1pf(expf(vv));          // softplus
          if (res) vv += res[(size_t)row*ldc + col];
          C[(size_t)row*ldc + col] = vv;
        }
      }
    }
  }
}

// ============== MFMA GEMM, m97-structure: global_load_lds staging ===========
// 128x128 tile, BK=32, 4 waves (64x64 subtile = 4x4 frags of 16x16x32).
// 3 MFMA per fragment pair: ahi*bhi + ahi*blo + alo*bhi (rel err ~2^-16).
// LDS 32 KB: A rows [0,1024), B rows [1024,2048); each row = 128 B = 8 slots
// of 16 B; logical slots 0-3 = hi k-chunks, 4-7 = lo k-chunks; physical slot
// = logical ^ (row&7). Staged via global_load_lds(16B): linear LDS dest +
// pre-swizzled per-lane global source (rule 21: source perm == read perm).
// Reads: every 8 consecutive lanes cover all 8 slots -> conflict-free.
// REV: read A rows time-reversed per batch (row ^ 2047).
// OUT: 0 = fp32 C (+bias/res), 1 = split-K raw partials, 2 = gelu -> bf16 hi/lo
template<int ACT, int OUT, bool REV>
__global__ __launch_bounds__(256,3) void gemm_mfma(
    const ushort* __restrict__ Ah_g, const ushort* __restrict__ Al_g, int ldaA,
    const ushort* __restrict__ Wh_g, const ushort* __restrict__ Wl_g,
    const float* __restrict__ bias, float* __restrict__ C,
    ushort* __restrict__ Oh, ushort* __restrict__ Ol,
    int ldc, const float* __restrict__ res,
    int M, int N, int K, int Kc)
{
  __shared__ short8b L[2048];          // 32 KB
  const int tid = threadIdx.x;
  const int m0 = blockIdx.y*128, n0 = blockIdx.x*128;
  const int lane = tid & 63, wv = tid >> 6;
  const int wr = (wv>>1)*64, wc = (wv&1)*64;       // wave's 64x64 subtile
  const int li = lane & 15, lg = lane >> 4;
  const int kbeg = (OUT==1) ? blockIdx.z*Kc : 0;
  const int nkt = ((OUT==1) ? Kc : K) >> 5;

  // staging: lane l fills LDS row (base + (l>>3)), phys slot (l&7), which must
  // hold logical slot sl = (l&7) ^ (l>>3): hi chunk sl (<4) or lo chunk sl-4.
  const int lr8 = lane >> 3, ls = lane & 7;
  const int sl = ls ^ lr8;
  const int chunk = (sl & 3) * 8;                  // k-elem offset of 16B piece
  const ushort* gA = (sl < 4) ? Ah_g : Al_g;
  const ushort* gB = (sl < 4) ? Wh_g : Wl_g;
  const ushort* aAddr[4]; const ushort* bAddr[4];
  #pragma unroll
  for (int i=0;i<4;i++){
    int rg = m0 + wv*32 + i*8 + lr8;
    if constexpr (REV) rg ^= (SEQ_-1);             // per-batch time reversal
    aAddr[i] = gA + (size_t)rg*ldaA + kbeg + chunk;
    int rb = n0 + wv*32 + i*8 + lr8;
    bAddr[i] = gB + (size_t)rb*K + kbeg + chunk;
  }

  f32x4 acc[4][4];
  #pragma unroll
  for (int i=0;i<4;i++)
    #pragma unroll
    for (int j=0;j<4;j++) acc[i][j] = (f32x4){0.f,0.f,0.f,0.f};

  for (int kt=0; kt<nkt; ++kt){
    const int ko = kt*32;                          // k-elems this tile
    #pragma unroll
    for (int i=0;i<4;i++){
      __builtin_amdgcn_global_load_lds((gas_u32*)(aAddr[i]+ko),
          (las_u32*)&L[(wv*32+i*8)*8], 16, 0, 0);
      __builtin_amdgcn_global_load_lds((gas_u32*)(bAddr[i]+ko),
          (las_u32*)&L[1024+(wv*32+i*8)*8], 16, 0, 0);
    }
    __syncthreads();                               // vmcnt drain + barrier
    short8b afh[4],afl[4],bfh[4],bfl[4];
    #pragma unroll
    for (int f=0; f<4; f++){
      int sa = (wr+f*16+li)*8 + (lg ^ (li&7));
      int sb = 1024 + (wc+f*16+li)*8 + (lg ^ (li&7));
      afh[f]=L[sa]; afl[f]=L[sa^4];
      bfh[f]=L[sb]; bfl[f]=L[sb^4];
    }
    #pragma unroll
    for (int fr=0;fr<4;fr++)
      #pragma unroll
      for (int fc=0;fc<4;fc++){
        acc[fr][fc]=__builtin_amdgcn_mfma_f32_16x16x32_bf16(afh[fr],bfh[fc],acc[fr][fc],0,0,0);
        acc[fr][fc]=__builtin_amdgcn_mfma_f32_16x16x32_bf16(afh[fr],bfl[fc],acc[fr][fc],0,0,0);
        acc[fr][fc]=__builtin_amdgcn_mfma_f32_16x16x32_bf16(afl[fr],bfh[fc],acc[fr][fc],0,0,0);
      }
    __syncthreads();                               // LDS consumed before restage
  }

  // C/D layout (m89-verified): col = lane&15, row = (lane>>4)*4 + reg
  if constexpr (OUT==1){
    float* P = C + (size_t)blockIdx.z*((size_t)M*N);
    #pragma unroll
    for (int fr=0;fr<4;fr++)
      #pragma unroll
      for (int fc=0;fc<4;fc++){
        int col = n0 + wc + fc*16 + li;
        int row = m0 + wr + fr*16 + lg*4;
        #pragma unroll
        for (int rg=0;rg<4;rg++)
          P[(size_t)(row+rg)*N + col] = acc[fr][fc][rg];
      }
  } else if constexpr (OUT==2){
    #pragma unroll
    for (int fr=0;fr<4;fr++)
      #pragma unroll
      for (int fc=0;fc<4;fc++){
        int col = n0 + wc + fc*16 + li;
        int row = m0 + wr + fr*16 + lg*4;
        float bv = bias ? bias[col] : 0.f;
        #pragma unroll
        for (int rg=0;rg<4;rg++){
          float t = acc[fr][fc][rg] + bv;
          t = 0.5f*t*(1.f+erff(t*0.70710678118654752f));   // exact gelu
          ushort h, lo_;
          split1(t, h, lo_);
          Oh[(size_t)(row+rg)*ldc + col] = h;
          Ol[(size_t)(row+rg)*ldc + col] = lo_;
        }
      }
  } else {
    #pragma unroll
    for (int fr=0;fr<4;fr++)
      #pragma unroll
      for (int fc=0;fc<4;fc++){
        int col = n0 + wc + fc*16 + li;
        int row = m0 + wr + fr*16 + lg*4;
        float bv = bias ? bias[col] : 0.f;
        #pragma unroll
        for (int rg=0;rg<4;rg++){
          float t = acc[fr][fc][rg] + bv;
          if (res) t += res[(size_t)(row+rg)*ldc + col];
          C[(size_t)(row+rg)*ldc + col] = t;
        }
      }
  }
}

// ---------------- split-K reduce: C = sum_k P[k] (+bias) (+res) --------------
__global__ __launch_bounds__(256) void reduce_split(const float* __restrict__ P,
    const float* __restrict__ bias, const float* __restrict__ res,
    float* __restrict__ C, int N, size_t elems, int nsplit)
{
  size_t i = ((size_t)blockIdx.x*256 + threadIdx.x)*4;
  float4 s = *(const float4*)(P + i);
  for (int k=1;k<nsplit;k++){
    float4 p = *(const float4*)(P + (size_t)k*elems + i);
    s.x+=p.x; s.y+=p.y; s.z+=p.z; s.w+=p.w;
  }
  if (bias){
    int col = (int)(i % (size_t)N);
    const float4 b = *(const float4*)(bias + col);
    s.x+=b.x; s.y+=b.y; s.z+=b.z; s.w+=b.w;
  }
  if (res){
    const float4 r = *(const float4*)(res + i);
    s.x+=r.x; s.y+=r.y; s.z+=r.z; s.w+=r.w;
  }
  *(float4*)(C + i) = s;
}

// ---------------- depthwise causal conv(4) + SiLU ----------------
__global__ __launch_bounds__(256) void conv_silu_kernel(const float* __restrict__ xz,
    const float* __restrict__ cw, const float* __restrict__ cb, float* __restrict__ xh)
{
  int idx = blockIdx.x*256 + threadIdx.x;   // over MR*DH
  int d = idx % DH;
  int row = idx / DH;
  int l = row & (SEQ_-1);
  const float* base = xz + (size_t)row*(2*DH) + d;
  float acc = cb[d];
  #pragma unroll
  for (int j=0;j<4;j++){
    int ll = l - 3 + j;
    if (ll >= 0) acc += cw[d*4+j] * base[(ptrdiff_t)(j-3)*(2*DH)];
  }
  xh[(size_t)row*DH + d] = acc * sigmoidf_(acc);
}

// ================= chunked selective scan, d-coalesced =================
// Phase 1: local scan from h=0 over CL steps -> hend[unit*NS+n], dtsum.
__global__ __launch_bounds__(256) void scan_p1_kernel(
    const float* __restrict__ dt0, const float* __restrict__ xh0, const float* __restrict__ xd0,
    const float* __restrict__ Al0,
    const float* __restrict__ dt1, const float* __restrict__ xh1, const float* __restrict__ xd1,
    const float* __restrict__ Al1,
    float* __restrict__ hend, float* __restrict__ dtsum)
{
  int tid = threadIdx.x;
  int bid = blockIdx.x;
  int dblk = bid % NDBLK;
  int t   = bid / NDBLK;          // db*NCH + c
  int c   = t & (NCH-1);
  int db  = t >> 5;               // dir*2 + b
  int dir = db >> 1, bb = db & 1;
  int d = dblk*256 + tid;
  const float* dt = dir ? dt1 : dt0;
  const float* xh = dir ? xh1 : xh0;
  const float* xd = dir ? xd1 : xd0;
  const float* Al = dir ? Al1 : Al0;

  __shared__ float sB[CL][NS];    // 4 KB
  {
    const float* xdb = xd + ((size_t)bb*SEQ_ + (size_t)c*CL)*80 + RK;
    int row = tid >> 2, part = tid & 3;   // 256 float4 = CL*NS floats
    *(float4*)&sB[row][part*4] = *(const float4*)(xdb + (size_t)row*80 + part*4);
  }
  float An[NS];
  {
    const float4* ap = (const float4*)(Al + (size_t)d*NS);
    #pragma unroll
    for (int q=0;q<4;q++){
      float4 a = ap[q];
      An[4*q+0] = -__expf(a.x); An[4*q+1] = -__expf(a.y);
      An[4*q+2] = -__expf(a.z); An[4*q+3] = -__expf(a.w);
    }
  }
  __syncthreads();

  float h[NS];
  #pragma unroll
  for (int n=0;n<NS;n++) h[n] = 0.f;
  float dts = 0.f;
  size_t base = ((size_t)bb*SEQ_ + (size_t)c*CL)*DH + d;
  #pragma unroll 4
  for (int l=0;l<CL;++l){
    float dtv = dt[base], uv = xh[base];
    float du = dtv*uv;
    float Bv[NS];
    *(float4*)&Bv[0]  = *(const float4*)&sB[l][0];
    *(float4*)&Bv[4]  = *(const float4*)&sB[l][4];
    *(float4*)&Bv[8]  = *(const float4*)&sB[l][8];
    *(float4*)&Bv[12] = *(const float4*)&sB[l][12];
    #pragma unroll
    for (int n=0;n<NS;n++)
      h[n] = h[n]*__expf(dtv*An[n]) + du*Bv[n];
    dts += dtv;
    base += DH;
  }
  size_t unit = ((size_t)db*DH + d)*NCH + c;
  float4* hp = (float4*)(hend + unit*NS);
  hp[0] = make_float4(h[0],h[1],h[2],h[3]);
  hp[1] = make_float4(h[4],h[5],h[6],h[7]);
  hp[2] = make_float4(h[8],h[9],h[10],h[11]);
  hp[3] = make_float4(h[12],h[13],h[14],h[15]);
  dtsum[(size_t)c*NCHAN + (size_t)db*DH + d] = dts;   // [c][ch] layout: coalesced
}

// Phase 2: per (channel, n): sequential over NCH chunks; hend -> hstart prefix.
__global__ __launch_bounds__(256) void scan_p2_kernel(
    const float* __restrict__ Al0, const float* __restrict__ Al1,
    float* __restrict__ hend, const float* __restrict__ dtsum)
{
  int t = blockIdx.x*256 + threadIdx.x;      // 0 .. NCHAN*NS-1
  int n = t & 15;
  int ch = t >> 4;
  int d  = ch % DH;
  int dir = (ch / DH) >> 1;
  const float* Al = dir ? Al1 : Al0;
  float An = -__expf(Al[d*NS + n]);
  float h0 = 0.f;
  size_t ub = (size_t)ch * NCH;
  #pragma unroll
  for (int c = 0; c < NCH; ++c) {
    float P  = __expf(An * dtsum[(size_t)c*NCHAN + ch]);
    float he = hend[(ub + c)*NS + n];
    hend[(ub + c)*NS + n] = h0;              // now holds hstart for chunk c
    h0 = h0 * P + he;
  }
}

// Phase 3: recurrence from hstart; gated output -> bf16 hi/lo into the dead
// x-half of xz: per row (4*DH ushorts of x-slot) = [hi: d=0..DH) [lo: d=0..DH).
__global__ __launch_bounds__(256) void scan_p3_kernel(
    const float* __restrict__ dt0, const float* __restrict__ xh0, const float* __restrict__ xd0,
    const float* __restrict__ z0, const float* __restrict__ Al0, const float* __restrict__ Dp0,
    ushort* __restrict__ yg0,
    const float* __restrict__ dt1, const float* __restrict__ xh1, const float* __restrict__ xd1,
    const float* __restrict__ z1, const float* __restrict__ Al1, const float* __restrict__ Dp1,
    ushort* __restrict__ yg1,
    const float* __restrict__ hstart)
{
  int tid = threadIdx.x;
  int bid = blockIdx.x;
  int dblk = bid % NDBLK;
  int t   = bid / NDBLK;
  int c   = t & (NCH-1);
  int db  = t >> 5;
  int dir = db >> 1, bb = db & 1;
  int d = dblk*256 + tid;
  const float* dt = dir ? dt1 : dt0;
  const float* xh = dir ? xh1 : xh0;
  const float* xd = dir ? xd1 : xd0;
  const float* zp = dir ? z1  : z0;
  const float* Al = dir ? Al1 : Al0;
  const float* Dp = dir ? Dp1 : Dp0;
  ushort*      yg = dir ? yg1 : yg0;

  __shared__ float sBC[CL][2*NS];   // 8 KB
  {
    const float* xdb = xd + ((size_t)bb*SEQ_ + (size_t)c*CL)*80 + RK;
    #pragma unroll
    for (int i=0;i<2;i++){
      int idx = tid + i*256;        // 512 float4 = CL*2*NS floats
      int row = idx >> 3, part = idx & 7;
      *(float4*)&sBC[row][part*4] = *(const float4*)(xdb + (size_t)row*80 + part*4);
    }
  }
  float An[NS];
  {
    const float4* ap = (const float4*)(Al + (size_t)d*NS);
    #pragma unroll
    for (int q=0;q<4;q++){
      float4 a = ap[q];
      An[4*q+0] = -__expf(a.x); An[4*q+1] = -__expf(a.y);
      An[4*q+2] = -__expf(a.z); An[4*q+3] = -__expf(a.w);
    }
  }
  float Dd = Dp[d];
  __syncthreads();

  size_t unit = ((size_t)db*DH + d)*NCH + c;
  float h[NS];
  {
    const float4* hp = (const float4*)(hstart + unit*NS);
    float4 h0=hp[0], h1=hp[1], h2=hp[2], h3=hp[3];
    h[0]=h0.x; h[1]=h0.y; h[2]=h0.z; h[3]=h0.w;
    h[4]=h1.x; h[5]=h1.y; h[6]=h1.z; h[7]=h1.w;
    h[8]=h2.x; h[9]=h2.y; h[10]=h2.z; h[11]=h2.w;
    h[12]=h3.x; h[13]=h3.y; h[14]=h3.z; h[15]=h3.w;
  }
  size_t base = ((size_t)bb*SEQ_ + (size_t)c*CL)*DH + d;
  size_t zidx = ((size_t)bb*SEQ_ + (size_t)c*CL)*(size_t)(2*DH) + DH + d;
  size_t yrow = ((size_t)bb*SEQ_ + (size_t)c*CL)*(size_t)(4*DH) + d;
  #pragma unroll 2
  for (int l=0;l<CL;++l){
    float dtv = dt[base], uv = xh[base];
    float zv = zp[zidx];
    float du = dtv*uv;
    float Bv[NS], Cv[NS];
    *(float4*)&Bv[0]  = *(const float4*)&sBC[l][0];
    *(float4*)&Bv[4]  = *(const float4*)&sBC[l][4];
    *(float4*)&Bv[8]  = *(const float4*)&sBC[l][8];
    *(float4*)&Bv[12] = *(const float4*)&sBC[l][12];
    *(float4*)&Cv[0]  = *(const float4*)&sBC[l][16];
    *(float4*)&Cv[4]  = *(const float4*)&sBC[l][20];
    *(float4*)&Cv[8]  = *(const float4*)&sBC[l][24];
    *(float4*)&Cv[12] = *(const float4*)&sBC[l][28];
    float y = 0.f;
    #pragma unroll
    for (int n=0;n<NS;n++){
      h[n] = h[n]*__expf(dtv*An[n]) + du*Bv[n];
      y = fmaf(h[n], Cv[n], y);
    }
    float yv = (y + uv*Dd) * (zv * sigmoidf_(zv));
    ushort hh, ll;
    split1(yv, hh, ll);
    yg[yrow] = hh; yg[yrow + DH] = ll;
    base += DH; zidx += 2*DH; yrow += 4*DH;
  }
}

template<int ACT>
static inline void launch_gemm(const float* A, int lda, const float* W, const float* bias,
                               float* C, int ldc, const float* res,
                               int M, int N, int K, hipStream_t s)
{
  dim3 grid((N+63)/64, M/64);
  gemm_nt<ACT,false><<<grid, dim3(256), 0, s>>>(A, lda, W, bias, C, ldc, res, M, N, K, 0);
}

static inline void launch_gemm_splitk(const float* A, int lda, const float* W,
                                      float* P, int M, int N, int K, int nsplit,
                                      hipStream_t s)
{
  dim3 grid((N+63)/64, M/64, nsplit);
  gemm_nt<0,true><<<grid, dim3(256), 0, s>>>(A, lda, W, nullptr, P, N, nullptr,
                                             M, N, K, K/nsplit);
}

extern "C" void kernel_launch(void* const* d_in, const int* in_sizes, int n_in,
                              void* d_out, int out_size, void* d_ws, size_t ws_size,
                              hipStream_t stream)
{
  const float* x        = (const float*)d_in[0];
  const float* f_in_w   = (const float*)d_in[1];
  const float* f_conv_w = (const float*)d_in[2];
  const float* f_conv_b = (const float*)d_in[3];
  const float* f_xproj  = (const float*)d_in[4];
  const float* f_dt_w   = (const float*)d_in[5];
  const float* f_dt_b   = (const float*)d_in[6];
  const float* f_A_log  = (const float*)d_in[7];
  const float* f_D      = (const float*)d_in[8];
  const float* f_out_w  = (const float*)d_in[9];
  const float* b_in_w   = (const float*)d_in[10];
  const float* b_conv_w = (const float*)d_in[11];
  const float* b_conv_b = (const float*)d_in[12];
  const float* b_xproj  = (const float*)d_in[13];
  const float* b_dt_w   = (const float*)d_in[14];
  const float* b_dt_b   = (const float*)d_in[15];
  const float* b_A_log  = (const float*)d_in[16];
  const float* b_D      = (const float*)d_in[17];
  const float* b_out_w  = (const float*)d_in[18];
  const float* ln1_g    = (const float*)d_in[19];
  const float* ln1_b    = (const float*)d_in[20];
  const float* ln2_g    = (const float*)d_in[21];
  const float* ln2_b    = (const float*)d_in[22];
  const float* ff_w1    = (const float*)d_in[23];
  const float* ff_b1    = (const float*)d_in[24];
  const float* ff_w2    = (const float*)d_in[25];
  const float* ff_b2    = (const float*)d_in[26];
  float* out = (float*)d_out;

  float* ws = (float*)d_ws;
  size_t o = 0;
  float* xz_f   = ws + o; o += (size_t)MR*2*DH;     // 12,582,912
  float* xz_b   = ws + o; o += (size_t)MR*2*DH;
  float* xh_f   = ws + o; o += (size_t)MR*DH;       // 6,291,456
  float* xh_b   = ws + o; o += (size_t)MR*DH;
  float* xdbl_f = ws + o; o += (size_t)MR*80;       // 327,680
  float* xdbl_b = ws + o; o += (size_t)MR*80;
  float* dtb_f  = ws + o; o += (size_t)MR*DH;
  float* dtb_b  = ws + o; o += (size_t)MR*DH;
  float* xnbf   = ws + o; o += (size_t)MR*DM;       // 2 ushort arrays MR*DM (hi,lo)
  float* dtsum  = ws + o; o += (size_t)NCHAN*NCH;   // 196,608
  float* wbf    = ws + o; o += (size_t)2*(2*DH*DM); // 4,718,592 fl = 9,437,184 ush
  // total: 59,047,936 floats = 236.2 MB

  // bf16 activation buffers
  ushort* xnh = (ushort*)xnbf;
  ushort* xnl = xnh + (size_t)MR*DM;
  // yg hi/lo live in the dead x-half of xz ([row][4*DH ushorts]: hi then lo)
  ushort* yg_f = (ushort*)xz_f;
  ushort* yg_b = (ushort*)xz_b;
  // weight region (time-shared: in_w -> out_w -> ff)
  ushort* wreg = (ushort*)wbf;
  ushort* f_inh = wreg;                       ushort* f_inl = wreg + (size_t)2*DH*DM;
  ushort* b_inh = wreg + (size_t)2*(2*DH*DM); ushort* b_inl = wreg + (size_t)3*(2*DH*DM);
  ushort* f_oth = wreg;                       ushort* f_otl = wreg + (size_t)DM*DH;
  ushort* b_oth = wreg + (size_t)2*DM*DH;     ushort* b_otl = wreg + (size_t)3*DM*DH;
  ushort* w1h   = wreg;                       ushort* w1l   = wreg + (size_t)4*DM*DM;
  ushort* w2h   = wreg + (size_t)2*(4*DM*DM); ushort* w2l   = wreg + (size_t)3*(4*DM*DM);
  // aliases (lifetime-safe reuse; stream is in-order)
  float* hend  = xnbf;                        // 3,145,728 fl == xnbf exactly (xn dead after in-proj)
  float* partX = xnbf;                        // xproj split-K partials: 8*MR*80 = 2.62M < 3.15M
                                              // (xn dead after in-proj; hend written after reduce)
  ushort* mh   = (ushort*)xh_f;               // ln2 out (xh dead after p3)
  ushort* ml   = mh + (size_t)MR*DM;
  float* fo    = xh_b;                        // out-proj results (xh_b dead after p3)
  float* bo    = xh_b + (size_t)MR*DM;
  float* part1 = dtb_f;                       // out-proj partials: 4*EL = dtb_f+dtb_b exactly
  ushort* ffhh = (ushort*)dtb_f;              // ff1 out bf16 (dtb dead after part1's last read)
  ushort* ffhl = ffhh + (size_t)MR*4*DM;
  float* part2 = xz_b;                        // ff_w2 partials (yg_b/z_b dead after out-proj)
  const size_t EL = (size_t)MR*DM;            // 3,145,728 (partial stride)
  const size_t EL2 = (size_t)MR*80;           // 327,680 (xproj partial stride)

  // 0) in-proj weight splits (fp32 -> bf16 hi/lo)
  split_kernel<<<(2*DH*DM/4+255)/256, 256, 0, stream>>>(f_in_w, f_inh, f_inl, 2*DH*DM/4);
  split_kernel<<<(2*DH*DM/4+255)/256, 256, 0, stream>>>(b_in_w, b_inh, b_inl, 2*DH*DM/4);
  // 1) LN1 -> bf16 hi/lo
  ln1_kernel<<<MR, 256, 0, stream>>>(x, ln1_g, ln1_b, xnh, xnl);
  // 2) in-proj both dirs (M=4096, N=3072, K=768); b reads A rows reversed
  {
    dim3 grid((2*DH)/128, MR/128);
    gemm_mfma<0,0,false><<<grid, dim3(256), 0, stream>>>(xnh, xnl, DM, f_inh, f_inl,
        nullptr, xz_f, nullptr, nullptr, 2*DH, nullptr, MR, 2*DH, DM, 0);
    gemm_mfma<0,0,true><<<grid, dim3(256), 0, stream>>>(xnh, xnl, DM, b_inh, b_inl,
        nullptr, xz_b, nullptr, nullptr, 2*DH, nullptr, MR, 2*DH, DM, 0);
  }
  // 2b) out-proj weight splits (in_w region now dead)
  split_kernel<<<(DM*DH/4+255)/256, 256, 0, stream>>>(f_out_w, f_oth, f_otl, DM*DH/4);
  split_kernel<<<(DM*DH/4+255)/256, 256, 0, stream>>>(b_out_w, b_oth, b_otl, DM*DH/4);
  // 3) depthwise conv + SiLU
  conv_silu_kernel<<<(MR*DH)/256, 256, 0, stream>>>(xz_f, f_conv_w, f_conv_b, xh_f);
  conv_silu_kernel<<<(MR*DH)/256, 256, 0, stream>>>(xz_b, b_conv_w, b_conv_b, xh_b);
  // 4) x_dbl = xh @ xproj^T (N=80, K=1536): split-K x8 + reduce (latency fix)
  launch_gemm_splitk(xh_f, DH, f_xproj, partX, MR, 80, DH, 8, stream);
  reduce_split<<<(int)(EL2/1024), 256, 0, stream>>>(partX, nullptr, nullptr, xdbl_f, 80, EL2, 8);
  launch_gemm_splitk(xh_b, DH, b_xproj, partX, MR, 80, DH, 8, stream);
  reduce_split<<<(int)(EL2/1024), 256, 0, stream>>>(partX, nullptr, nullptr, xdbl_b, 80, EL2, 8);
  // 5) dt = softplus(dt_in @ dt_w^T + dt_b)   (K=48) — skinny, fp32
  launch_gemm<1>(xdbl_f, 80, f_dt_w, f_dt_b, dtb_f, DH, nullptr, MR, DH, RK, stream);
  launch_gemm<1>(xdbl_b, 80, b_dt_w, b_dt_b, dtb_b, DH, nullptr, MR, DH, RK, stream);
  // 6) chunked selective scan; gated output -> bf16 hi/lo into xz x-half
  scan_p1_kernel<<<4*NCH*NDBLK, 256, 0, stream>>>(
      dtb_f, xh_f, xdbl_f, f_A_log,
      dtb_b, xh_b, xdbl_b, b_A_log,
      hend, dtsum);
  scan_p2_kernel<<<(NCHAN*NS)/256, 256, 0, stream>>>(f_A_log, b_A_log, hend, dtsum);
  scan_p3_kernel<<<4*NCH*NDBLK, 256, 0, stream>>>(
      dtb_f, xh_f, xdbl_f, xz_f, f_A_log, f_D, yg_f,
      dtb_b, xh_b, xdbl_b, xz_b, b_A_log, b_D, yg_b,
      hend);
  // 7) out-proj per direction (N=768, K=1536): MFMA split-K x4 + reduce
  {
    dim3 grid(DM/128, MR/128, 4);
    gemm_mfma<0,1,false><<<grid, dim3(256), 0, stream>>>(yg_f, yg_f + DH, 4*DH,
        f_oth, f_otl, nullptr, part1, nullptr, nullptr, DM, nullptr, MR, DM, DH, DH/4);
    reduce_split<<<(int)(EL/1024), 256, 0, stream>>>(part1, nullptr, nullptr, fo, DM, EL, 4);
    gemm_mfma<0,1,false><<<grid, dim3(256), 0, stream>>>(yg_b, yg_b + DH, 4*DH,
        b_oth, b_otl, nullptr, part1, nullptr, nullptr, DM, nullptr, MR, DM, DH, DH/4);
    reduce_split<<<(int)(EL/1024), 256, 0, stream>>>(part1, nullptr, nullptr, bo, DM, EL, 4);
  }
  // 7b) FFN weight splits (out_w region now dead)
  split_kernel<<<(4*DM*DM/4+255)/256, 256, 0, stream>>>(ff_w1, w1h, w1l, 4*DM*DM/4);
  split_kernel<<<(4*DM*DM/4+255)/256, 256, 0, stream>>>(ff_w2, w2h, w2l, 4*DM*DM/4);
  // 8) LN2 of fo + reverse(bo) -> bf16 hi/lo
  ln2_kernel<<<MR, 256, 0, stream>>>(fo, bo, ln2_g, ln2_b, mh, ml);
  // 9) FFN: w1 (N=3072,K=768) + gelu -> bf16 hi/lo; w2 (N=768,K=3072) split-K x4
  {
    dim3 grid1((4*DM)/128, MR/128);
    gemm_mfma<2,2,false><<<grid1, dim3(256), 0, stream>>>(mh, ml, DM, w1h, w1l,
        ff_b1, nullptr, ffhh, ffhl, 4*DM, nullptr, MR, 4*DM, DM, 0);
    dim3 grid2(DM/128, MR/128, 4);
    gemm_mfma<0,1,false><<<grid2, dim3(256), 0, stream>>>(ffhh, ffhl, 4*DM, w2h, w2l,
        nullptr, part2, nullptr, nullptr, DM, nullptr, MR, DM, 4*DM, (4*DM)/4);
    reduce_split<<<(int)(EL/1024), 256, 0, stream>>>(part2, ff_b2, x, out, DM, EL, 4);
  }
}